// Round 2
// baseline (549.135 us; speedup 1.0000x reference)
//
#include <hip/hip_runtime.h>
#include <hip/hip_bf16.h>

// MultiHeadAttention fused pipeline for MI355X (gfx950).
// B=4, S=2048, E=768, H=12, D=64.
// Stages:
//   1) Q/K/V projections: bf16 MFMA GEMM [8192x768]@[768x768]+bias
//      -> Qh,Kh as [BH][S][D] bf16 ; V written transposed [BH][D][S] bf16
//   2) flash attention per (bh, 128-q-row tile), online softmax, bf16 MFMA
//      -> ctx [8192][768] bf16
//   3) out projection GEMM (bf16 in, fp32 out)

typedef __bf16 bf16x8 __attribute__((ext_vector_type(8)));
typedef float floatx4 __attribute__((ext_vector_type(4)));

#define MFMA_BF16(a, b, c) __builtin_amdgcn_mfma_f32_16x16x32_bf16(a, b, c, 0, 0, 0)

// MFMA 16x16x32 layouts (verified, learn_hip m89/m91):
//   A frag: A[m = lane&15][k = (lane>>4)*8 + j]   j=0..7 contiguous
//   B frag: B[k = (lane>>4)*8 + j][n = lane&15]
//   C/D  : C[m = (lane>>4)*4 + r][n = lane&15]    r=0..3

// ---------------------------------------------------------------------------
// GEMM: Y = X[ M x K ] @ W[ K x N ] + bias.  M=8192, K=768, N=768.
// IN_BF16: 0 -> X is fp32, 1 -> X is bf16.
// MODE: 0 -> write bf16 to [BH][S][D] layout (Q/K)
//       1 -> write bf16 to [BH][D][S] layout (V transposed)
//       2 -> write fp32 plain row-major (final output)
// Block 256 threads (4 waves). Tile 64(M) x 64(N), K-step 32.
// Wave w computes a 32x32 sub-tile: (w>>1)*32 rows, (w&1)*32 cols.
// ---------------------------------------------------------------------------
template <int IN_BF16, int MODE>
__global__ __launch_bounds__(256) void gemm_kernel(const void* __restrict__ Xv,
                                                   const float* __restrict__ W,
                                                   const float* __restrict__ bias,
                                                   void* __restrict__ Yv) {
  constexpr int K = 768, N = 768;
  __shared__ __bf16 As[64][40];   // 64 rows x 32 k (pad 40 to spread banks)
  __shared__ __bf16 Bst[64][40];  // transposed: [n][k], pad 40

  const int m0 = blockIdx.x * 64;
  const int n0 = blockIdx.y * 64;
  const int tid = threadIdx.x;
  const int lane = tid & 63;
  const int w = tid >> 6;
  const int quad = lane >> 4;
  const int l16 = lane & 15;
  const int wm = (w >> 1) * 32;
  const int wn = (w & 1) * 32;

  // staging assignments
  const int arow = tid >> 2;          // 0..63
  const int acol = (tid & 3) * 8;     // 0,8,16,24
  const int brow = tid >> 3;          // 0..31 (k within chunk)
  const int bcol = (tid & 7) * 8;     // 0..56 (n within tile)

  const float* Xf = (const float*)Xv;
  const __bf16* Xb = (const __bf16*)Xv;

  floatx4 acc[2][2] = {};

  for (int k0 = 0; k0 < K; k0 += 32) {
    __syncthreads();
    // ---- stage A tile (64 x 32) as bf16
    if (IN_BF16) {
      bf16x8 v = *(const bf16x8*)&Xb[(size_t)(m0 + arow) * K + k0 + acol];
      *(bf16x8*)&As[arow][acol] = v;
    } else {
      const float* p = &Xf[(size_t)(m0 + arow) * K + k0 + acol];
      float4 f0 = *(const float4*)p;
      float4 f1 = *(const float4*)(p + 4);
      bf16x8 v;
      v[0] = (__bf16)f0.x; v[1] = (__bf16)f0.y; v[2] = (__bf16)f0.z; v[3] = (__bf16)f0.w;
      v[4] = (__bf16)f1.x; v[5] = (__bf16)f1.y; v[6] = (__bf16)f1.z; v[7] = (__bf16)f1.w;
      *(bf16x8*)&As[arow][acol] = v;
    }
    // ---- stage B tile transposed: Bst[n][k] = W[k0+k][n0+n]
    {
      const float* p = &W[(size_t)(k0 + brow) * N + n0 + bcol];
      float4 f0 = *(const float4*)p;
      float4 f1 = *(const float4*)(p + 4);
      Bst[bcol + 0][brow] = (__bf16)f0.x;
      Bst[bcol + 1][brow] = (__bf16)f0.y;
      Bst[bcol + 2][brow] = (__bf16)f0.z;
      Bst[bcol + 3][brow] = (__bf16)f0.w;
      Bst[bcol + 4][brow] = (__bf16)f1.x;
      Bst[bcol + 5][brow] = (__bf16)f1.y;
      Bst[bcol + 6][brow] = (__bf16)f1.z;
      Bst[bcol + 7][brow] = (__bf16)f1.w;
    }
    __syncthreads();
    // ---- MFMA on the 32-K chunk
    bf16x8 a[2], b[2];
    a[0] = *(const bf16x8*)&As[wm + l16][quad * 8];
    a[1] = *(const bf16x8*)&As[wm + 16 + l16][quad * 8];
    b[0] = *(const bf16x8*)&Bst[wn + l16][quad * 8];
    b[1] = *(const bf16x8*)&Bst[wn + 16 + l16][quad * 8];
#pragma unroll
    for (int mg = 0; mg < 2; ++mg)
#pragma unroll
      for (int ng = 0; ng < 2; ++ng) acc[mg][ng] = MFMA_BF16(a[mg], b[ng], acc[mg][ng]);
  }

  // ---- epilogue
#pragma unroll
  for (int mg = 0; mg < 2; ++mg) {
#pragma unroll
    for (int ng = 0; ng < 2; ++ng) {
      const int n = n0 + wn + ng * 16 + l16;
      const float bv = bias[n];
#pragma unroll
      for (int r = 0; r < 4; ++r) {
        const int m = m0 + wm + mg * 16 + quad * 4 + r;
        const float val = acc[mg][ng][r] + bv;
        if (MODE == 2) {
          ((float*)Yv)[(size_t)m * N + n] = val;
        } else {
          const int bb = m >> 11, s = m & 2047;
          const int h = n >> 6, d = n & 63;
          __bf16* Y = (__bf16*)Yv;
          if (MODE == 0)
            Y[((size_t)(bb * 12 + h) * 2048 + s) * 64 + d] = (__bf16)val;
          else
            Y[((size_t)(bb * 12 + h) * 64 + d) * 2048 + s] = (__bf16)val;
        }
      }
    }
  }
}

// ---------------------------------------------------------------------------
// Flash attention. grid = (S/128, BH) = (16, 48), block = 256 (4 waves).
// Each wave handles 32 q rows (2 row-groups of 16). Keys iterated in tiles
// of 64 with online softmax. K/V fragments loaded straight from global
// (L2-resident: 256KB per head). P goes through per-wave LDS to convert
// C-layout -> A-layout.
// ---------------------------------------------------------------------------
__global__ __launch_bounds__(256) void attn_kernel(const __bf16* __restrict__ Qh,
                                                   const __bf16* __restrict__ Kh,
                                                   const __bf16* __restrict__ Vt,
                                                   const int* __restrict__ mask,
                                                   __bf16* __restrict__ ctx) {
  const int bh = blockIdx.y;
  const int b = bh / 12;
  const int h = bh - b * 12;
  const int tid = threadIdx.x;
  const int lane = tid & 63;
  const int w = tid >> 6;
  const int quad = lane >> 4;
  const int l16 = lane & 15;
  const int q0 = blockIdx.x * 128 + w * 32;

  __shared__ float biasS[2048];
  __shared__ __bf16 Plds[4][32][72];  // per-wave P scratch, rows padded to 72

  for (int i = tid; i < 2048; i += 256) biasS[i] = mask[b * 2048 + i] ? 0.0f : -1e9f;
  __syncthreads();

  const __bf16* Qbase = Qh + (size_t)bh * 2048 * 64;
  const __bf16* Kbase = Kh + (size_t)bh * 2048 * 64;
  const __bf16* Vbase = Vt + (size_t)bh * 64 * 2048;

  // Q A-fragments: rows q0+mg*16+l16, k-dim (d) chunks of 32
  bf16x8 aq[2][2];
#pragma unroll
  for (int mg = 0; mg < 2; ++mg)
#pragma unroll
    for (int c = 0; c < 2; ++c)
      aq[mg][c] = *(const bf16x8*)&Qbase[(size_t)(q0 + mg * 16 + l16) * 64 + c * 32 + quad * 8];

  floatx4 o[2][4] = {};
  float rM[2][4], rL[2][4];
#pragma unroll
  for (int mg = 0; mg < 2; ++mg)
#pragma unroll
    for (int r = 0; r < 4; ++r) {
      rM[mg][r] = -1e30f;
      rL[mg][r] = 0.0f;
    }

  for (int kt = 0; kt < 2048; kt += 64) {
    // ---- scores: S = Q @ K^T  (2 row-groups x 4 key-tiles of 16)
    floatx4 sc[2][4];
#pragma unroll
    for (int t = 0; t < 4; ++t) {
      const __bf16* kr = &Kbase[(size_t)(kt + t * 16 + l16) * 64 + quad * 8];
      bf16x8 bk0 = *(const bf16x8*)kr;
      bf16x8 bk1 = *(const bf16x8*)(kr + 32);
#pragma unroll
      for (int mg = 0; mg < 2; ++mg) {
        floatx4 zero = {};
        floatx4 s = MFMA_BF16(aq[mg][0], bk0, zero);
        s = MFMA_BF16(aq[mg][1], bk1, s);
        sc[mg][t] = s;
      }
    }
    // scale + padding-mask bias
    float kb[4];
#pragma unroll
    for (int t = 0; t < 4; ++t) kb[t] = biasS[kt + t * 16 + l16];
#pragma unroll
    for (int mg = 0; mg < 2; ++mg)
#pragma unroll
      for (int t = 0; t < 4; ++t)
#pragma unroll
        for (int r = 0; r < 4; ++r) sc[mg][t][r] = sc[mg][t][r] * 0.125f + kb[t];

    // ---- online softmax update
#pragma unroll
    for (int mg = 0; mg < 2; ++mg) {
#pragma unroll
      for (int r = 0; r < 4; ++r) {
        float mx = sc[mg][0][r];
        mx = fmaxf(mx, sc[mg][1][r]);
        mx = fmaxf(mx, sc[mg][2][r]);
        mx = fmaxf(mx, sc[mg][3][r]);
        mx = fmaxf(mx, __shfl_xor(mx, 1, 64));
        mx = fmaxf(mx, __shfl_xor(mx, 2, 64));
        mx = fmaxf(mx, __shfl_xor(mx, 4, 64));
        mx = fmaxf(mx, __shfl_xor(mx, 8, 64));
        const float m_new = fmaxf(rM[mg][r], mx);
        const float alpha = __expf(rM[mg][r] - m_new);
        rM[mg][r] = m_new;
        float rs = 0.0f;
#pragma unroll
        for (int t = 0; t < 4; ++t) {
          const float p = __expf(sc[mg][t][r] - m_new);
          sc[mg][t][r] = p;
          rs += p;
        }
        rs += __shfl_xor(rs, 1, 64);
        rs += __shfl_xor(rs, 2, 64);
        rs += __shfl_xor(rs, 4, 64);
        rs += __shfl_xor(rs, 8, 64);
        rL[mg][r] = rL[mg][r] * alpha + rs;
#pragma unroll
        for (int t = 0; t < 4; ++t) o[mg][t][r] *= alpha;
      }
    }

    // ---- P: C-layout -> LDS -> A-layout
#pragma unroll
    for (int mg = 0; mg < 2; ++mg)
#pragma unroll
      for (int t = 0; t < 4; ++t)
#pragma unroll
        for (int r = 0; r < 4; ++r)
          Plds[w][mg * 16 + quad * 4 + r][t * 16 + l16] = (__bf16)sc[mg][t][r];
    __syncthreads();  // uniform across all 4 waves every iteration

    bf16x8 ap[2][2];
#pragma unroll
    for (int mg = 0; mg < 2; ++mg)
#pragma unroll
      for (int c = 0; c < 2; ++c)
        ap[mg][c] = *(const bf16x8*)&Plds[w][mg * 16 + l16][c * 32 + quad * 8];

    // ---- O += P @ V   (V transposed: Vt[d][s])
#pragma unroll
    for (int t = 0; t < 4; ++t) {
#pragma unroll
      for (int c = 0; c < 2; ++c) {
        bf16x8 bv = *(const bf16x8*)&Vbase[(size_t)(t * 16 + l16) * 2048 + kt + c * 32 + quad * 8];
#pragma unroll
        for (int mg = 0; mg < 2; ++mg) o[mg][t] = MFMA_BF16(ap[mg][c], bv, o[mg][t]);
      }
    }
  }

  // ---- epilogue: normalize, write ctx [B*S][768] bf16
#pragma unroll
  for (int mg = 0; mg < 2; ++mg) {
#pragma unroll
    for (int t = 0; t < 4; ++t) {
#pragma unroll
      for (int r = 0; r < 4; ++r) {
        const int q = q0 + mg * 16 + quad * 4 + r;
        const float val = o[mg][t][r] / rL[mg][r];
        ctx[(size_t)(b * 2048 + q) * 768 + h * 64 + t * 16 + l16] = (__bf16)val;
      }
    }
  }
}

// ---------------------------------------------------------------------------
extern "C" void kernel_launch(void* const* d_in, const int* in_sizes, int n_in,
                              void* d_out, int out_size, void* d_ws, size_t ws_size,
                              hipStream_t stream) {
  const float* q = (const float*)d_in[0];
  const float* k = (const float*)d_in[1];
  const float* v = (const float*)d_in[2];
  const int* mask = (const int*)d_in[3];
  const float* Wq = (const float*)d_in[4];
  const float* bq = (const float*)d_in[5];
  const float* Wk = (const float*)d_in[6];
  const float* bk = (const float*)d_in[7];
  const float* Wv = (const float*)d_in[8];
  const float* bv = (const float*)d_in[9];
  const float* Wo = (const float*)d_in[10];
  const float* bo = (const float*)d_in[11];
  float* out = (float*)d_out;

  char* ws = (char*)d_ws;
  const size_t SZ = (size_t)8192 * 768 * 2;  // 12.58 MB per bf16 buffer
  __bf16* Qh = (__bf16*)(ws);
  __bf16* Kh = (__bf16*)(ws + SZ);
  __bf16* Vt = (__bf16*)(ws + 2 * SZ);
  __bf16* ctx = (__bf16*)(ws + 3 * SZ);

  dim3 gg(128, 12), blk(256);
  gemm_kernel<0, 0><<<gg, blk, 0, stream>>>(q, Wq, bq, Qh);
  gemm_kernel<0, 0><<<gg, blk, 0, stream>>>(k, Wk, bk, Kh);
  gemm_kernel<0, 1><<<gg, blk, 0, stream>>>(v, Wv, bv, Vt);
  attn_kernel<<<dim3(16, 48), blk, 0, stream>>>(Qh, Kh, Vt, mask, ctx);
  gemm_kernel<1, 2><<<gg, blk, 0, stream>>>(ctx, Wo, bo, out);
}

// Round 3
// 394.730 us; speedup vs baseline: 1.3912x; 1.3912x over previous
//
#include <hip/hip_runtime.h>
#include <hip/hip_bf16.h>
#include <stdint.h>

// MultiHeadAttention fused pipeline for MI355X (gfx950).
// B=4, S=2048, E=768, H=12, D=64.
//  prep_convert:  q,k,v fp32 -> bf16 row-major X[8192][768]
//  prep_transpose: W[768][768] fp32 -> Wt[768][768] bf16 (Wt[n][k] = W[k][n])
//  qkv_gemm (z=0,1,2): C[m=e][n=s] = Wt @ X^T, epilogue scatters to
//     Qh,Kh [BH][S][64] (b64 packed) / Vt [BH][64][S] (scalar)
//  attn: S^T = K Q^T orientation, fixed-reference softmax (no max pass),
//     P^T via per-wave LDS (b64 writes, b128 reads), O^T = V^T P^T.
//  out_gemm: C[m=e][n=s] = Wto @ ctx^T, float4 stores to d_out.

typedef __bf16 bf16x8 __attribute__((ext_vector_type(8)));
typedef __bf16 bf16x4 __attribute__((ext_vector_type(4)));
typedef float floatx4 __attribute__((ext_vector_type(4)));

#define MFMA_BF16(a, b, c) __builtin_amdgcn_mfma_f32_16x16x32_bf16(a, b, c, 0, 0, 0)

// MFMA 16x16x32 layouts (verified, learn_hip m89/m91):
//   A frag: A[m = lane&15][k = (lane>>4)*8 + j]
//   B frag: B[k = (lane>>4)*8 + j][n = lane&15]   (i.e. read from [n][k] storage)
//   C/D  : C[m = (lane>>4)*4 + r][n = lane&15]

__device__ __forceinline__ void glds16(const __bf16* g, __bf16* l) {
  __builtin_amdgcn_global_load_lds(
      (const __attribute__((address_space(1))) unsigned int*)g,
      (__attribute__((address_space(3))) unsigned int*)l, 16, 0, 0);
}

// ---------------------------------------------------------------------------
// prep: fp32 -> bf16 convert of q,k,v. grid (3072, 3), block 256.
// ---------------------------------------------------------------------------
__global__ __launch_bounds__(256) void prep_convert(
    const float* __restrict__ q, const float* __restrict__ k,
    const float* __restrict__ v, __bf16* __restrict__ Xq,
    __bf16* __restrict__ Xk, __bf16* __restrict__ Xv) {
  const int z = blockIdx.y;
  const float* src = (z == 0) ? q : (z == 1) ? k : v;
  __bf16* dst = (z == 0) ? Xq : (z == 1) ? Xk : Xv;
  const size_t i8 = ((size_t)blockIdx.x * 256 + threadIdx.x) * 8;
  float4 f0 = *(const float4*)&src[i8];
  float4 f1 = *(const float4*)&src[i8 + 4];
  bf16x8 o;
  o[0] = (__bf16)f0.x; o[1] = (__bf16)f0.y; o[2] = (__bf16)f0.z; o[3] = (__bf16)f0.w;
  o[4] = (__bf16)f1.x; o[5] = (__bf16)f1.y; o[6] = (__bf16)f1.z; o[7] = (__bf16)f1.w;
  *(bf16x8*)&dst[i8] = o;
}

// ---------------------------------------------------------------------------
// prep: transpose+convert weights. grid (24, 24, 4), block 256.
// Wt[n][k] = (bf16) W[k][n]
// ---------------------------------------------------------------------------
__global__ __launch_bounds__(256) void prep_transpose(
    const float* __restrict__ W0, const float* __restrict__ W1,
    const float* __restrict__ W2, const float* __restrict__ W3,
    __bf16* __restrict__ T0, __bf16* __restrict__ T1,
    __bf16* __restrict__ T2, __bf16* __restrict__ T3) {
  const int z = blockIdx.z;
  const float* W = (z == 0) ? W0 : (z == 1) ? W1 : (z == 2) ? W2 : W3;
  __bf16* T = (z == 0) ? T0 : (z == 1) ? T1 : (z == 2) ? T2 : T3;
  __shared__ float t[32][33];
  const int tx = threadIdx.x & 31, ty = threadIdx.x >> 5;
  const int kb = blockIdx.x * 32, nb = blockIdx.y * 32;
#pragma unroll
  for (int j = 0; j < 4; ++j)
    t[ty + j * 8][tx] = W[(size_t)(kb + ty + j * 8) * 768 + nb + tx];
  __syncthreads();
#pragma unroll
  for (int j = 0; j < 4; ++j)
    T[(size_t)(nb + ty + j * 8) * 768 + kb + tx] = (__bf16)t[tx][ty + j * 8];
}

// ---------------------------------------------------------------------------
// NT GEMM mainloop: C[m][n] = sum_k Aop[m][k] * Bop[n][k]; both [dim][768]
// bf16 k-contiguous. Tile 128x128, BK=32, 24 iters, global_load_lds staging.
// Wave w owns 64x64 quadrant: wm=(w>>1)*64, wn=(w&1)*64.
// ---------------------------------------------------------------------------
__device__ __forceinline__ void gemm_nt_mainloop(
    const __bf16* __restrict__ Aop, const __bf16* __restrict__ Bop,
    int m0, int n0, __bf16* As, __bf16* Bs, floatx4 acc[4][4]) {
  const int tid = threadIdx.x;
  const int lane = tid & 63;
  const int w = tid >> 6;
  const int quad = lane >> 4;
  const int l16 = lane & 15;
  const int wm = (w >> 1) * 64;
  const int wn = (w & 1) * 64;

  // glds: wave w, inst j covers LDS bytes [w*2048 + j*1024, +1024)
  // = rows w*32 + j*16 + (lane>>2), col bytes (lane&3)*16 of the 128x32 tile.
  const int grow = w * 32 + (lane >> 2);
  const int gcol = (lane & 3) * 8;
  const __bf16* gA = Aop + (size_t)(m0 + grow) * 768 + gcol;
  const __bf16* gB = Bop + (size_t)(n0 + grow) * 768 + gcol;
  __bf16* lA = As + w * 1024;  // elems (= w*2048 bytes); HW appends lane*16B
  __bf16* lB = Bs + w * 1024;

  for (int k0 = 0; k0 < 768; k0 += 32) {
    __syncthreads();
    glds16(gA, lA);
    glds16(gA + (size_t)16 * 768, lA + 512);
    glds16(gB, lB);
    glds16(gB + (size_t)16 * 768, lB + 512);
    gA += 32;
    gB += 32;
    __syncthreads();  // compiler emits s_waitcnt vmcnt(0) before barrier
    bf16x8 af[4], bfr[4];
#pragma unroll
    for (int t = 0; t < 4; ++t) {
      af[t] = *(const bf16x8*)&As[(wm + t * 16 + l16) * 32 + quad * 8];
      bfr[t] = *(const bf16x8*)&Bs[(wn + t * 16 + l16) * 32 + quad * 8];
    }
#pragma unroll
    for (int mt = 0; mt < 4; ++mt)
#pragma unroll
      for (int nt = 0; nt < 4; ++nt)
        acc[mt][nt] = MFMA_BF16(af[mt], bfr[nt], acc[mt][nt]);
  }
}

// ---------------------------------------------------------------------------
// QKV projection GEMM. grid (6, 64, 3), block 256.
// C[m=e_out][n=s]. z<2 -> Qh/Kh [BH][S][64] b64-packed; z=2 -> Vt [BH][64][S].
// ---------------------------------------------------------------------------
__global__ __launch_bounds__(256) void qkv_gemm(
    const __bf16* __restrict__ Wtq, const __bf16* __restrict__ Wtk,
    const __bf16* __restrict__ Wtv, const __bf16* __restrict__ Xq,
    const __bf16* __restrict__ Xk, const __bf16* __restrict__ Xv,
    const float* __restrict__ bq, const float* __restrict__ bk,
    const float* __restrict__ bv, __bf16* __restrict__ Qh,
    __bf16* __restrict__ Kh, __bf16* __restrict__ Vt) {
  __shared__ __align__(16) __bf16 As[128 * 32];
  __shared__ __align__(16) __bf16 Bs[128 * 32];
  const int z = blockIdx.z;
  const __bf16* Aop = (z == 0) ? Wtq : (z == 1) ? Wtk : Wtv;
  const __bf16* Bop = (z == 0) ? Xq : (z == 1) ? Xk : Xv;
  const float* bias = (z == 0) ? bq : (z == 1) ? bk : bv;
  __bf16* Dst = (z == 0) ? Qh : (z == 1) ? Kh : Vt;
  const int m0 = blockIdx.x * 128, n0 = blockIdx.y * 128;

  floatx4 acc[4][4] = {};
  gemm_nt_mainloop(Aop, Bop, m0, n0, As, Bs, acc);

  const int tid = threadIdx.x, lane = tid & 63, w = tid >> 6;
  const int quad = lane >> 4, l16 = lane & 15;
  const int wm = (w >> 1) * 64, wn = (w & 1) * 64;
#pragma unroll
  for (int mt = 0; mt < 4; ++mt) {
    const int e = m0 + wm + mt * 16 + quad * 4;
    const float4 b4 = *(const float4*)&bias[e];
    const int h = e >> 6, d = e & 63;
#pragma unroll
    for (int nt = 0; nt < 4; ++nt) {
      const int s = n0 + wn + nt * 16 + l16;
      const int bb = s >> 11, sr = s & 2047;
      const float v0 = acc[mt][nt][0] + b4.x;
      const float v1 = acc[mt][nt][1] + b4.y;
      const float v2 = acc[mt][nt][2] + b4.z;
      const float v3 = acc[mt][nt][3] + b4.w;
      if (z < 2) {
        bf16x4 pv;
        pv[0] = (__bf16)v0; pv[1] = (__bf16)v1; pv[2] = (__bf16)v2; pv[3] = (__bf16)v3;
        *(bf16x4*)&Dst[((size_t)(bb * 12 + h) * 2048 + sr) * 64 + d] = pv;
      } else {
        const size_t base = ((size_t)(bb * 12 + h) * 64 + d) * 2048 + sr;
        Dst[base] = (__bf16)v0;
        Dst[base + 2048] = (__bf16)v1;
        Dst[base + 4096] = (__bf16)v2;
        Dst[base + 6144] = (__bf16)v3;
      }
    }
  }
}

// ---------------------------------------------------------------------------
// Output projection GEMM. grid (6, 64), block 256. C[m=e][n=s] fp32 out.
// ---------------------------------------------------------------------------
__global__ __launch_bounds__(256) void out_gemm(const __bf16* __restrict__ Wto,
                                                const __bf16* __restrict__ Ctx,
                                                const float* __restrict__ bo,
                                                float* __restrict__ Out) {
  __shared__ __align__(16) __bf16 As[128 * 32];
  __shared__ __align__(16) __bf16 Bs[128 * 32];
  const int m0 = blockIdx.x * 128, n0 = blockIdx.y * 128;
  floatx4 acc[4][4] = {};
  gemm_nt_mainloop(Wto, Ctx, m0, n0, As, Bs, acc);

  const int tid = threadIdx.x, lane = tid & 63, w = tid >> 6;
  const int quad = lane >> 4, l16 = lane & 15;
  const int wm = (w >> 1) * 64, wn = (w & 1) * 64;
#pragma unroll
  for (int mt = 0; mt < 4; ++mt) {
    const int e = m0 + wm + mt * 16 + quad * 4;
    const float4 b4 = *(const float4*)&bo[e];
#pragma unroll
    for (int nt = 0; nt < 4; ++nt) {
      const int s = n0 + wn + nt * 16 + l16;
      float4 r;
      r.x = acc[mt][nt][0] + b4.x;
      r.y = acc[mt][nt][1] + b4.y;
      r.z = acc[mt][nt][2] + b4.z;
      r.w = acc[mt][nt][3] + b4.w;
      *(float4*)&Out[(size_t)s * 768 + e] = r;
    }
  }
}

// ---------------------------------------------------------------------------
// Flash attention, S^T orientation. grid (16, 48), block 256 (4 waves),
// wave handles 32 q rows x all 2048 keys in 64-key tiles.
//   scores:  S^T[key][q] = K(A-frag, from Kh) x Q(B-frag, from Qh)
//   softmax: p = exp(s*0.125 + bias), fixed reference (no running max);
//            per-lane partial sums, single cross-lane reduce at end.
//   P^T:     C-layout gives 4 consecutive keys/lane -> b64 LDS writes into
//            Plds[q][key]; PV B-frags read back as b128. Per-wave private,
//            NO barrier in the loop.
//   PV:      O^T[d][q] = V^T(A-frag, from Vt) x P^T(B-frag).
// ---------------------------------------------------------------------------
__global__ __launch_bounds__(256) void attn_kernel(
    const __bf16* __restrict__ Qh, const __bf16* __restrict__ Kh,
    const __bf16* __restrict__ Vt, const int* __restrict__ mask,
    __bf16* __restrict__ ctx) {
  const int bh = blockIdx.y, b = bh / 12, h = bh - b * 12;
  const int tid = threadIdx.x, lane = tid & 63, w = tid >> 6;
  const int quad = lane >> 4, l16 = lane & 15;
  const int q0 = blockIdx.x * 128 + w * 32;

  __shared__ float biasS[2048];
  __shared__ __align__(16) __bf16 Plds[4][32][72];  // [wave][q][key(+pad)]

  for (int i = tid; i < 2048; i += 256) biasS[i] = mask[b * 2048 + i] ? 0.0f : -1e9f;
  __syncthreads();

  const __bf16* Qbase = Qh + (size_t)bh * 2048 * 64;
  const __bf16* Kbase = Kh + (size_t)bh * 2048 * 64;
  const __bf16* Vbase = Vt + (size_t)bh * 64 * 2048;

  // Q B-frags: B[k=d][n=q] read from Qh[q][d] (i.e. [n][k] storage)
  bf16x8 bqf[2][2];
#pragma unroll
  for (int qt = 0; qt < 2; ++qt)
#pragma unroll
    for (int c = 0; c < 2; ++c)
      bqf[qt][c] =
          *(const bf16x8*)&Qbase[(size_t)(q0 + qt * 16 + l16) * 64 + c * 32 + quad * 8];

  floatx4 o[4][2] = {};  // O^T accs: [d-tile][q-tile]
  float rS[2] = {0.0f, 0.0f};

  for (int kt = 0; kt < 2048; kt += 64) {
    // ---- scores S^T: 4 key-tiles x 2 q-tiles
    floatx4 sc[4][2];
#pragma unroll
    for (int t = 0; t < 4; ++t) {
      const __bf16* kr = &Kbase[(size_t)(kt + t * 16 + l16) * 64 + quad * 8];
      bf16x8 ak0 = *(const bf16x8*)kr;
      bf16x8 ak1 = *(const bf16x8*)(kr + 32);
#pragma unroll
      for (int qt = 0; qt < 2; ++qt) {
        floatx4 zz = {};
        zz = MFMA_BF16(ak0, bqf[qt][0], zz);
        zz = MFMA_BF16(ak1, bqf[qt][1], zz);
        sc[t][qt] = zz;
      }
    }
    // ---- p = exp(s/8 + bias[key]); accumulate row sums in-register
#pragma unroll
    for (int t = 0; t < 4; ++t) {
      const float4 kb = *(const float4*)&biasS[kt + t * 16 + quad * 4];
#pragma unroll
      for (int qt = 0; qt < 2; ++qt) {
        floatx4 p;
        p[0] = __expf(sc[t][qt][0] * 0.125f + kb.x);
        p[1] = __expf(sc[t][qt][1] * 0.125f + kb.y);
        p[2] = __expf(sc[t][qt][2] * 0.125f + kb.z);
        p[3] = __expf(sc[t][qt][3] * 0.125f + kb.w);
        sc[t][qt] = p;
        rS[qt] += p[0] + p[1] + p[2] + p[3];
      }
    }
    // ---- pack P^T into Plds[q][key]: 4 consecutive keys per lane -> b64
#pragma unroll
    for (int qt = 0; qt < 2; ++qt)
#pragma unroll
      for (int t = 0; t < 4; ++t) {
        bf16x4 pv;
        pv[0] = (__bf16)sc[t][qt][0];
        pv[1] = (__bf16)sc[t][qt][1];
        pv[2] = (__bf16)sc[t][qt][2];
        pv[3] = (__bf16)sc[t][qt][3];
        *(bf16x4*)&Plds[w][qt * 16 + l16][t * 16 + quad * 4] = pv;
      }
    // ---- O^T += V^T @ P^T  (per-wave LDS, in-order DS pipe: no barrier)
#pragma unroll
    for (int c = 0; c < 2; ++c) {
      bf16x8 bp[2];
#pragma unroll
      for (int qt = 0; qt < 2; ++qt)
        bp[qt] = *(const bf16x8*)&Plds[w][qt * 16 + l16][c * 32 + quad * 8];
#pragma unroll
      for (int dt = 0; dt < 4; ++dt) {
        bf16x8 av =
            *(const bf16x8*)&Vbase[(size_t)(dt * 16 + l16) * 2048 + kt + c * 32 + quad * 8];
#pragma unroll
        for (int qt = 0; qt < 2; ++qt) o[dt][qt] = MFMA_BF16(av, bp[qt], o[dt][qt]);
      }
    }
  }

  // ---- final cross-lane sum reduce (quads only) + normalize + write ctx
  float inv[2];
#pragma unroll
  for (int qt = 0; qt < 2; ++qt) {
    float s = rS[qt];
    s += __shfl_xor(s, 16, 64);
    s += __shfl_xor(s, 32, 64);
    inv[qt] = 1.0f / s;
  }
#pragma unroll
  for (int dt = 0; dt < 4; ++dt)
#pragma unroll
    for (int qt = 0; qt < 2; ++qt) {
      const int q = q0 + qt * 16 + l16;
      const int d = h * 64 + dt * 16 + quad * 4;
      bf16x4 pv;
      pv[0] = (__bf16)(o[dt][qt][0] * inv[qt]);
      pv[1] = (__bf16)(o[dt][qt][1] * inv[qt]);
      pv[2] = (__bf16)(o[dt][qt][2] * inv[qt]);
      pv[3] = (__bf16)(o[dt][qt][3] * inv[qt]);
      *(bf16x4*)&ctx[(size_t)(b * 2048 + q) * 768 + d] = pv;
    }
}

// ---------------------------------------------------------------------------
extern "C" void kernel_launch(void* const* d_in, const int* in_sizes, int n_in,
                              void* d_out, int out_size, void* d_ws, size_t ws_size,
                              hipStream_t stream) {
  const float* q = (const float*)d_in[0];
  const float* k = (const float*)d_in[1];
  const float* v = (const float*)d_in[2];
  const int* mask = (const int*)d_in[3];
  const float* Wq = (const float*)d_in[4];
  const float* bq = (const float*)d_in[5];
  const float* Wk = (const float*)d_in[6];
  const float* bk = (const float*)d_in[7];
  const float* Wv = (const float*)d_in[8];
  const float* bv = (const float*)d_in[9];
  const float* Wo = (const float*)d_in[10];
  const float* bo = (const float*)d_in[11];
  float* out = (float*)d_out;

  char* ws = (char*)d_ws;
  const size_t SZ = (size_t)8192 * 768 * 2;   // 12.58 MB
  const size_t WSZ = (size_t)768 * 768 * 2;   // 1.18 MB
  __bf16* Xq = (__bf16*)(ws);
  __bf16* Xk = (__bf16*)(ws + SZ);
  __bf16* Xv = (__bf16*)(ws + 2 * SZ);
  __bf16* Qh = (__bf16*)(ws + 3 * SZ);
  __bf16* Kh = (__bf16*)(ws + 4 * SZ);
  __bf16* Vt = (__bf16*)(ws + 5 * SZ);
  __bf16* ctx = (__bf16*)(ws + 6 * SZ);
  __bf16* Wtq = (__bf16*)(ws + 7 * SZ);
  __bf16* Wtk = (__bf16*)(ws + 7 * SZ + WSZ);
  __bf16* Wtv = (__bf16*)(ws + 7 * SZ + 2 * WSZ);
  __bf16* Wto = (__bf16*)(ws + 7 * SZ + 3 * WSZ);

  prep_convert<<<dim3(3072, 3), 256, 0, stream>>>(q, k, v, Xq, Xk, Xv);
  prep_transpose<<<dim3(24, 24, 4), 256, 0, stream>>>(Wq, Wk, Wv, Wo, Wtq, Wtk, Wtv, Wto);
  qkv_gemm<<<dim3(6, 64, 3), 256, 0, stream>>>(Wtq, Wtk, Wtv, Xq, Xk, Xv, bq, bk, bv,
                                               Qh, Kh, Vt);
  attn_kernel<<<dim3(16, 48), 256, 0, stream>>>(Qh, Kh, Vt, mask, ctx);
  out_gemm<<<dim3(6, 64), 256, 0, stream>>>(Wto, ctx, bo, out);
}

// Round 5
// 333.865 us; speedup vs baseline: 1.6448x; 1.1823x over previous
//
#include <hip/hip_runtime.h>
#include <hip/hip_bf16.h>
#include <stdint.h>

// MultiHeadAttention fused pipeline for MI355X (gfx950).
// B=4, S=2048, E=768, H=12, D=64.
//  prep_transpose: W[768][768] fp32 -> Wt[768][768] bf16 (Wt[n][k] = W[k][n])
//  qkv_gemm (z=0,1,2): C[m=e][n=s] = Wt (A, glds) x X^T (B, fp32->bf16 inline
//     staged); epilogue scatters Qh,Kh [BH][S][64] b64 / Vt [BH][64][S].
//  attn: shared-LDS K/V tiles (glds16, m97 2-barrier loop), S^T = K Q^T,
//     fixed-reference softmax (exp2, no max pass), P^T via per-wave LDS.
//  out_gemm: C[m=e][n=s] = Wto x ctx^T (both glds), float4 stores.

typedef __bf16 bf16x8 __attribute__((ext_vector_type(8)));
typedef __bf16 bf16x4 __attribute__((ext_vector_type(4)));
typedef float floatx4 __attribute__((ext_vector_type(4)));

#define MFMA_BF16(a, b, c) __builtin_amdgcn_mfma_f32_16x16x32_bf16(a, b, c, 0, 0, 0)

// MFMA 16x16x32 layouts (verified, learn_hip m89/m91):
//   A frag: A[m = lane&15][k = (lane>>4)*8 + j]
//   B frag: B[k = (lane>>4)*8 + j][n = lane&15]   (read from [n][k] storage)
//   C/D  : C[m = (lane>>4)*4 + r][n = lane&15]
// glds16: LDS dest is wave-uniform base + lane*16B -> one instruction covers
// 1024 B. For 64-elem (128 B) rows: 8 rows/chunk, lane -> row lane>>3,
// col (lane&7)*8. For 32-elem (64 B) rows: 16 rows/chunk, lane -> row
// lane>>2, col (lane&3)*8.

__device__ __forceinline__ void glds16(const __bf16* g, __bf16* l) {
  __builtin_amdgcn_global_load_lds(
      (const __attribute__((address_space(1))) unsigned int*)g,
      (__attribute__((address_space(3))) unsigned int*)l, 16, 0, 0);
}

// ---------------------------------------------------------------------------
// prep: transpose+convert weights. grid (24, 24, 4), block 256.
// ---------------------------------------------------------------------------
__global__ __launch_bounds__(256) void prep_transpose(
    const float* __restrict__ W0, const float* __restrict__ W1,
    const float* __restrict__ W2, const float* __restrict__ W3,
    __bf16* __restrict__ T0, __bf16* __restrict__ T1,
    __bf16* __restrict__ T2, __bf16* __restrict__ T3) {
  const int z = blockIdx.z;
  const float* W = (z == 0) ? W0 : (z == 1) ? W1 : (z == 2) ? W2 : W3;
  __bf16* T = (z == 0) ? T0 : (z == 1) ? T1 : (z == 2) ? T2 : T3;
  __shared__ float t[32][33];
  const int tx = threadIdx.x & 31, ty = threadIdx.x >> 5;
  const int kb = blockIdx.x * 32, nb = blockIdx.y * 32;
#pragma unroll
  for (int j = 0; j < 4; ++j)
    t[ty + j * 8][tx] = W[(size_t)(kb + ty + j * 8) * 768 + nb + tx];
  __syncthreads();
#pragma unroll
  for (int j = 0; j < 4; ++j)
    T[(size_t)(nb + ty + j * 8) * 768 + kb + tx] = (__bf16)t[tx][ty + j * 8];
}

// ---------------------------------------------------------------------------
// QKV projection GEMM. grid (6, 64, 3), block 256.
// A = Wt (bf16, glds16). B = X (fp32 row-major [8192][768]) staged with
// inline fp32->bf16 convert. C[m=e][n=s]. Tile 128x128, BK=32.
// ---------------------------------------------------------------------------
__global__ __launch_bounds__(256) void qkv_gemm(
    const __bf16* __restrict__ Wtq, const __bf16* __restrict__ Wtk,
    const __bf16* __restrict__ Wtv, const float* __restrict__ Xq,
    const float* __restrict__ Xk, const float* __restrict__ Xv,
    const float* __restrict__ bq, const float* __restrict__ bk,
    const float* __restrict__ bv, __bf16* __restrict__ Qh,
    __bf16* __restrict__ Kh, __bf16* __restrict__ Vt) {
  __shared__ __align__(16) __bf16 As[128 * 32];
  __shared__ __align__(16) __bf16 Bs[128 * 32];
  const int z = blockIdx.z;
  const __bf16* Aop = (z == 0) ? Wtq : (z == 1) ? Wtk : Wtv;
  const float* Bop = (z == 0) ? Xq : (z == 1) ? Xk : Xv;
  const float* bias = (z == 0) ? bq : (z == 1) ? bk : bv;
  __bf16* Dst = (z == 0) ? Qh : (z == 1) ? Kh : Vt;
  const int m0 = blockIdx.x * 128, n0 = blockIdx.y * 128;

  const int tid = threadIdx.x, lane = tid & 63, w = tid >> 6;
  const int quad = lane >> 4, l16 = lane & 15;
  const int wm = (w >> 1) * 64, wn = (w & 1) * 64;

  // A staging (glds, 64 B rows): wave w insts j=0,1 -> rows w*32+j*16+(lane>>2)
  const int garow = w * 32 + (lane >> 2);
  const int gacol = (lane & 3) * 8;
  const __bf16* gA = Aop + (size_t)(m0 + garow) * 768 + gacol;
  __bf16* lA = As + w * 1024;  // elems; chunks of 512 elems per inst
  // B staging (explicit fp32): pass j covers rows (tid>>3)+32j, col (tid&7)*4
  const int brow = tid >> 3, bcol = (tid & 7) * 4;

  floatx4 acc[4][4] = {};

  for (int k0 = 0; k0 < 768; k0 += 32) {
    __syncthreads();
    glds16(gA, lA);
    glds16(gA + (size_t)16 * 768, lA + 512);
    gA += 32;
    float4 f[4];
#pragma unroll
    for (int j = 0; j < 4; ++j)
      f[j] = *(const float4*)&Bop[(size_t)(n0 + brow + 32 * j) * 768 + k0 + bcol];
#pragma unroll
    for (int j = 0; j < 4; ++j) {
      bf16x4 pv;
      pv[0] = (__bf16)f[j].x; pv[1] = (__bf16)f[j].y;
      pv[2] = (__bf16)f[j].z; pv[3] = (__bf16)f[j].w;
      *(bf16x4*)&Bs[(brow + 32 * j) * 32 + bcol] = pv;
    }
    __syncthreads();
    bf16x8 af[4], bfr[4];
#pragma unroll
    for (int t = 0; t < 4; ++t) {
      af[t] = *(const bf16x8*)&As[(wm + t * 16 + l16) * 32 + quad * 8];
      bfr[t] = *(const bf16x8*)&Bs[(wn + t * 16 + l16) * 32 + quad * 8];
    }
#pragma unroll
    for (int mt = 0; mt < 4; ++mt)
#pragma unroll
      for (int nt = 0; nt < 4; ++nt)
        acc[mt][nt] = MFMA_BF16(af[mt], bfr[nt], acc[mt][nt]);
  }

  // epilogue
#pragma unroll
  for (int mt = 0; mt < 4; ++mt) {
    const int e = m0 + wm + mt * 16 + quad * 4;
    const float4 b4 = *(const float4*)&bias[e];
    const int h = e >> 6, d = e & 63;
#pragma unroll
    for (int nt = 0; nt < 4; ++nt) {
      const int s = n0 + wn + nt * 16 + l16;
      const int bb = s >> 11, sr = s & 2047;
      const float v0 = acc[mt][nt][0] + b4.x;
      const float v1 = acc[mt][nt][1] + b4.y;
      const float v2 = acc[mt][nt][2] + b4.z;
      const float v3 = acc[mt][nt][3] + b4.w;
      if (z < 2) {
        bf16x4 pv;
        pv[0] = (__bf16)v0; pv[1] = (__bf16)v1; pv[2] = (__bf16)v2; pv[3] = (__bf16)v3;
        *(bf16x4*)&Dst[((size_t)(bb * 12 + h) * 2048 + sr) * 64 + d] = pv;
      } else {
        const size_t base = ((size_t)(bb * 12 + h) * 64 + d) * 2048 + sr;
        Dst[base] = (__bf16)v0;
        Dst[base + 2048] = (__bf16)v1;
        Dst[base + 4096] = (__bf16)v2;
        Dst[base + 6144] = (__bf16)v3;
      }
    }
  }
}

// ---------------------------------------------------------------------------
// Output projection GEMM. grid (6, 64), block 256. Both operands bf16, glds.
// ---------------------------------------------------------------------------
__global__ __launch_bounds__(256) void out_gemm(const __bf16* __restrict__ Wto,
                                                const __bf16* __restrict__ Ctx,
                                                const float* __restrict__ bo,
                                                float* __restrict__ Out) {
  __shared__ __align__(16) __bf16 As[128 * 32];
  __shared__ __align__(16) __bf16 Bs[128 * 32];
  const int m0 = blockIdx.x * 128, n0 = blockIdx.y * 128;
  const int tid = threadIdx.x, lane = tid & 63, w = tid >> 6;
  const int quad = lane >> 4, l16 = lane & 15;
  const int wm = (w >> 1) * 64, wn = (w & 1) * 64;

  const int grow = w * 32 + (lane >> 2);
  const int gcol = (lane & 3) * 8;
  const __bf16* gA = Wto + (size_t)(m0 + grow) * 768 + gcol;
  const __bf16* gB = Ctx + (size_t)(n0 + grow) * 768 + gcol;
  __bf16* lA = As + w * 1024;
  __bf16* lB = Bs + w * 1024;

  floatx4 acc[4][4] = {};
  for (int k0 = 0; k0 < 768; k0 += 32) {
    __syncthreads();
    glds16(gA, lA);
    glds16(gA + (size_t)16 * 768, lA + 512);
    glds16(gB, lB);
    glds16(gB + (size_t)16 * 768, lB + 512);
    gA += 32;
    gB += 32;
    __syncthreads();
    bf16x8 af[4], bfr[4];
#pragma unroll
    for (int t = 0; t < 4; ++t) {
      af[t] = *(const bf16x8*)&As[(wm + t * 16 + l16) * 32 + quad * 8];
      bfr[t] = *(const bf16x8*)&Bs[(wn + t * 16 + l16) * 32 + quad * 8];
    }
#pragma unroll
    for (int mt = 0; mt < 4; ++mt)
#pragma unroll
      for (int nt = 0; nt < 4; ++nt)
        acc[mt][nt] = MFMA_BF16(af[mt], bfr[nt], acc[mt][nt]);
  }

#pragma unroll
  for (int mt = 0; mt < 4; ++mt) {
    const int e = m0 + wm + mt * 16 + quad * 4;
    const float4 b4 = *(const float4*)&bo[e];
#pragma unroll
    for (int nt = 0; nt < 4; ++nt) {
      const int s = n0 + wn + nt * 16 + l16;
      float4 r;
      r.x = acc[mt][nt][0] + b4.x;
      r.y = acc[mt][nt][1] + b4.y;
      r.z = acc[mt][nt][2] + b4.z;
      r.w = acc[mt][nt][3] + b4.w;
      *(float4*)&Out[(size_t)s * 768 + e] = r;
    }
  }
}

// ---------------------------------------------------------------------------
// Flash attention, shared-LDS K/V tiles. grid (16, 48), block 256 (4 waves).
// Per 64-key tile: stage K[64 key][64 d] and V[64 d][64 key] into LDS via
// glds16 (m97 2-barrier pattern): 8 chunks of 1024 B (8 rows each); wave w
// stages chunks w*2 and w*2+1 of each tile.
// S^T = K Q^T orientation; fixed-reference softmax via exp2 (no max pass);
// per-lane partial sums reduced once at end. P^T via per-wave LDS
// (b64 writes / b128 reads, no barrier). O^T = V^T P^T.
// ---------------------------------------------------------------------------
__global__ __launch_bounds__(256) void attn_kernel(
    const __bf16* __restrict__ Qh, const __bf16* __restrict__ Kh,
    const __bf16* __restrict__ Vt, const int* __restrict__ mask,
    __bf16* __restrict__ ctx) {
  const int bh = blockIdx.y, b = bh / 12, h = bh - b * 12;
  const int tid = threadIdx.x, lane = tid & 63, w = tid >> 6;
  const int quad = lane >> 4, l16 = lane & 15;
  const int q0 = blockIdx.x * 128 + w * 32;

  __shared__ float biasS[2048];                       // pre-scaled (log2 dom)
  __shared__ __align__(16) __bf16 Ks[64 * 64];        // [key][d]
  __shared__ __align__(16) __bf16 Vs[64 * 64];        // [d][key]
  __shared__ __align__(16) __bf16 Plds[4][32][72];    // [wave][q][key(+pad)]

  for (int i = tid; i < 2048; i += 256)
    biasS[i] = mask[b * 2048 + i] ? 0.0f : -1e5f;
  __syncthreads();

  const __bf16* Qbase = Qh + (size_t)bh * 2048 * 64;
  const __bf16* Kbase = Kh + (size_t)bh * 2048 * 64;
  const __bf16* Vbase = Vt + (size_t)bh * 64 * 2048;

  // Q B-frags: B[k=d][n=q] read from Qh[q][d]
  bf16x8 bqf[2][2];
#pragma unroll
  for (int qt = 0; qt < 2; ++qt)
#pragma unroll
    for (int c = 0; c < 2; ++c)
      bqf[qt][c] =
          *(const bf16x8*)&Qbase[(size_t)(q0 + qt * 16 + l16) * 64 + c * 32 + quad * 8];

  // staging (128 B rows): chunk c covers rows c*8 + (lane>>3), col (lane&7)*8,
  // LDS dest base + c*512 elems (HW appends lane*16 B).
  const int srow = (lane >> 3);
  const int scol = (lane & 7) * 8;

  floatx4 o[4][2] = {};  // O^T accs: [d-tile][q-tile]
  float rS[2] = {0.0f, 0.0f};
  const float SC = 0.18033688011112042f;  // 0.125 * log2(e)

  for (int kt = 0; kt < 2048; kt += 64) {
    __syncthreads();  // prior-iter LDS reads done
#pragma unroll
    for (int j = 0; j < 2; ++j) {
      const int c = w * 2 + j;
      const int row = c * 8 + srow;
      glds16(&Kbase[(size_t)(kt + row) * 64 + scol], Ks + c * 512);
      glds16(&Vbase[(size_t)row * 2048 + kt + scol], Vs + c * 512);
    }
    __syncthreads();  // staging visible (compiler drains vmcnt before barrier)

    // ---- scores S^T: 4 key-tiles x 2 q-tiles
    floatx4 sc[4][2];
#pragma unroll
    for (int t = 0; t < 4; ++t) {
      bf16x8 ak0 = *(const bf16x8*)&Ks[(t * 16 + l16) * 64 + quad * 8];
      bf16x8 ak1 = *(const bf16x8*)&Ks[(t * 16 + l16) * 64 + 32 + quad * 8];
#pragma unroll
      for (int qt = 0; qt < 2; ++qt) {
        floatx4 zz = {};
        zz = MFMA_BF16(ak0, bqf[qt][0], zz);
        zz = MFMA_BF16(ak1, bqf[qt][1], zz);
        sc[t][qt] = zz;
      }
    }
    // ---- p = exp2(s*SC + bias2[key]); accumulate per-lane sums
#pragma unroll
    for (int t = 0; t < 4; ++t) {
      const float4 kb = *(const float4*)&biasS[kt + t * 16 + quad * 4];
#pragma unroll
      for (int qt = 0; qt < 2; ++qt) {
        floatx4 p;
        p[0] = exp2f(fmaf(sc[t][qt][0], SC, kb.x));
        p[1] = exp2f(fmaf(sc[t][qt][1], SC, kb.y));
        p[2] = exp2f(fmaf(sc[t][qt][2], SC, kb.z));
        p[3] = exp2f(fmaf(sc[t][qt][3], SC, kb.w));
        sc[t][qt] = p;
        rS[qt] += p[0] + p[1] + p[2] + p[3];
      }
    }
    // ---- pack P^T into Plds[q][key] (4 consecutive keys/lane -> b64)
#pragma unroll
    for (int qt = 0; qt < 2; ++qt)
#pragma unroll
      for (int t = 0; t < 4; ++t) {
        bf16x4 pv;
        pv[0] = (__bf16)sc[t][qt][0];
        pv[1] = (__bf16)sc[t][qt][1];
        pv[2] = (__bf16)sc[t][qt][2];
        pv[3] = (__bf16)sc[t][qt][3];
        *(bf16x4*)&Plds[w][qt * 16 + l16][t * 16 + quad * 4] = pv;
      }
    // ---- O^T += V^T @ P^T  (per-wave Plds; in-wave lgkmcnt only)
#pragma unroll
    for (int c = 0; c < 2; ++c) {
      bf16x8 bp[2];
#pragma unroll
      for (int qt = 0; qt < 2; ++qt)
        bp[qt] = *(const bf16x8*)&Plds[w][qt * 16 + l16][c * 32 + quad * 8];
#pragma unroll
      for (int dt = 0; dt < 4; ++dt) {
        bf16x8 av = *(const bf16x8*)&Vs[(dt * 16 + l16) * 64 + c * 32 + quad * 8];
#pragma unroll
        for (int qt = 0; qt < 2; ++qt) o[dt][qt] = MFMA_BF16(av, bp[qt], o[dt][qt]);
      }
    }
  }

  // ---- cross-lane sum (across quads) + normalize + write ctx
  float inv[2];
#pragma unroll
  for (int qt = 0; qt < 2; ++qt) {
    float s = rS[qt];
    s += __shfl_xor(s, 16, 64);
    s += __shfl_xor(s, 32, 64);
    inv[qt] = 1.0f / s;
  }
#pragma unroll
  for (int dt = 0; dt < 4; ++dt)
#pragma unroll
    for (int qt = 0; qt < 2; ++qt) {
      const int q = q0 + qt * 16 + l16;
      const int d = h * 64 + dt * 16 + quad * 4;
      bf16x4 pv;
      pv[0] = (__bf16)(o[dt][qt][0] * inv[qt]);
      pv[1] = (__bf16)(o[dt][qt][1] * inv[qt]);
      pv[2] = (__bf16)(o[dt][qt][2] * inv[qt]);
      pv[3] = (__bf16)(o[dt][qt][3] * inv[qt]);
      *(bf16x4*)&ctx[(size_t)(b * 2048 + q) * 768 + d] = pv;
    }
}

// ---------------------------------------------------------------------------
extern "C" void kernel_launch(void* const* d_in, const int* in_sizes, int n_in,
                              void* d_out, int out_size, void* d_ws, size_t ws_size,
                              hipStream_t stream) {
  const float* q = (const float*)d_in[0];
  const float* k = (const float*)d_in[1];
  const float* v = (const float*)d_in[2];
  const int* mask = (const int*)d_in[3];
  const float* Wq = (const float*)d_in[4];
  const float* bq = (const float*)d_in[5];
  const float* Wk = (const float*)d_in[6];
  const float* bk = (const float*)d_in[7];
  const float* Wv = (const float*)d_in[8];
  const float* bv = (const float*)d_in[9];
  const float* Wo = (const float*)d_in[10];
  const float* bo = (const float*)d_in[11];
  float* out = (float*)d_out;

  char* ws = (char*)d_ws;
  const size_t SZ = (size_t)8192 * 768 * 2;   // 12.58 MB
  const size_t WSZ = (size_t)768 * 768 * 2;   // 1.18 MB
  __bf16* Qh = (__bf16*)(ws);
  __bf16* Kh = (__bf16*)(ws + SZ);
  __bf16* Vt = (__bf16*)(ws + 2 * SZ);
  __bf16* ctx = (__bf16*)(ws + 3 * SZ);
  __bf16* Wtq = (__bf16*)(ws + 4 * SZ);
  __bf16* Wtk = (__bf16*)(ws + 4 * SZ + WSZ);
  __bf16* Wtv = (__bf16*)(ws + 4 * SZ + 2 * WSZ);
  __bf16* Wto = (__bf16*)(ws + 4 * SZ + 3 * WSZ);

  prep_transpose<<<dim3(24, 24, 4), 256, 0, stream>>>(Wq, Wk, Wv, Wo, Wtq, Wtk, Wtv, Wto);
  qkv_gemm<<<dim3(6, 64, 3), 256, 0, stream>>>(Wtq, Wtk, Wtv, q, k, v, bq, bk, bv,
                                               Qh, Kh, Vt);
  attn_kernel<<<dim3(16, 48), 256, 0, stream>>>(Qh, Kh, Vt, mask, ctx);
  out_gemm<<<dim3(6, 64), 256, 0, stream>>>(Wto, ctx, bo, out);
}

// Round 6
// 320.185 us; speedup vs baseline: 1.7151x; 1.0427x over previous
//
#include <hip/hip_runtime.h>
#include <hip/hip_bf16.h>
#include <stdint.h>

// MultiHeadAttention fused pipeline for MI355X (gfx950).
// B=4, S=2048, E=768, H=12, D=64.
//  prep_convert: q,k,v fp32 -> bf16 X[8192][768]
//  prep_transpose: W fp32 -> Wt bf16 (Wt[n][k] = W[k][n])
//  qkv_gemm (z): C[m=e][n=s] = Wt x X^T (both glds16-staged bf16).
//     Epilogue: z=0 Qh plain [BH][S][64]; z=1 Kh same but XOR-swizzled cols
//     (block ^= s&7); z=2 Vt [BH][64][S] with per-64-window XOR swizzle
//     (key block ^= d&7). Swizzles kill LDS bank conflicts in attn since
//     glds16 copies global layout verbatim into LDS.
//  attn: shared-LDS K/V tiles, S^T = K Q^T, fixed-ref softmax (exp2),
//     P^T via per-wave LDS. Fragment reads use block = quad ^ (l16&7).
//  out_gemm: C[m=e][n=s] = Wto x ctx^T, float4 stores.

typedef __bf16 bf16x8 __attribute__((ext_vector_type(8)));
typedef __bf16 bf16x4 __attribute__((ext_vector_type(4)));
typedef float floatx4 __attribute__((ext_vector_type(4)));

#define MFMA_BF16(a, b, c) __builtin_amdgcn_mfma_f32_16x16x32_bf16(a, b, c, 0, 0, 0)

// MFMA 16x16x32 layouts (verified, learn_hip m89/m91):
//   A frag: A[m = lane&15][k = (lane>>4)*8 + j]
//   B frag: B[k = (lane>>4)*8 + j][n = lane&15]   (read from [n][k] storage)
//   C/D  : C[m = (lane>>4)*4 + r][n = lane&15]
// glds16: 64 lanes x 16 B = 1024 B per instruction, dest = uniform base +
// lane*16B. 128B rows -> 8 rows/chunk (lane>>3, (lane&7)*8); 64B rows ->
// 16 rows/chunk (lane>>2, (lane&3)*8).

__device__ __forceinline__ void glds16(const __bf16* g, __bf16* l) {
  __builtin_amdgcn_global_load_lds(
      (const __attribute__((address_space(1))) unsigned int*)g,
      (__attribute__((address_space(3))) unsigned int*)l, 16, 0, 0);
}

// ---------------------------------------------------------------------------
// prep: fp32 -> bf16 convert of q,k,v. grid (3072, 3), block 256.
// ---------------------------------------------------------------------------
__global__ __launch_bounds__(256) void prep_convert(
    const float* __restrict__ q, const float* __restrict__ k,
    const float* __restrict__ v, __bf16* __restrict__ Xq,
    __bf16* __restrict__ Xk, __bf16* __restrict__ Xv) {
  const int z = blockIdx.y;
  const float* src = (z == 0) ? q : (z == 1) ? k : v;
  __bf16* dst = (z == 0) ? Xq : (z == 1) ? Xk : Xv;
  const size_t i8 = ((size_t)blockIdx.x * 256 + threadIdx.x) * 8;
  float4 f0 = *(const float4*)&src[i8];
  float4 f1 = *(const float4*)&src[i8 + 4];
  bf16x8 o;
  o[0] = (__bf16)f0.x; o[1] = (__bf16)f0.y; o[2] = (__bf16)f0.z; o[3] = (__bf16)f0.w;
  o[4] = (__bf16)f1.x; o[5] = (__bf16)f1.y; o[6] = (__bf16)f1.z; o[7] = (__bf16)f1.w;
  *(bf16x8*)&dst[i8] = o;
}

// ---------------------------------------------------------------------------
// prep: transpose+convert weights. grid (24, 24, 4), block 256.
// ---------------------------------------------------------------------------
__global__ __launch_bounds__(256) void prep_transpose(
    const float* __restrict__ W0, const float* __restrict__ W1,
    const float* __restrict__ W2, const float* __restrict__ W3,
    __bf16* __restrict__ T0, __bf16* __restrict__ T1,
    __bf16* __restrict__ T2, __bf16* __restrict__ T3) {
  const int z = blockIdx.z;
  const float* W = (z == 0) ? W0 : (z == 1) ? W1 : (z == 2) ? W2 : W3;
  __bf16* T = (z == 0) ? T0 : (z == 1) ? T1 : (z == 2) ? T2 : T3;
  __shared__ float t[32][33];
  const int tx = threadIdx.x & 31, ty = threadIdx.x >> 5;
  const int kb = blockIdx.x * 32, nb = blockIdx.y * 32;
#pragma unroll
  for (int j = 0; j < 4; ++j)
    t[ty + j * 8][tx] = W[(size_t)(kb + ty + j * 8) * 768 + nb + tx];
  __syncthreads();
#pragma unroll
  for (int j = 0; j < 4; ++j)
    T[(size_t)(nb + ty + j * 8) * 768 + kb + tx] = (__bf16)t[tx][ty + j * 8];
}

// ---------------------------------------------------------------------------
// QKV projection GEMM. grid (6, 64, 3), block 256. Both operands bf16,
// glds16-staged. C[m=e][n=s]. Tile 128x128, BK=32.
// ---------------------------------------------------------------------------
__global__ __launch_bounds__(256) void qkv_gemm(
    const __bf16* __restrict__ Wtq, const __bf16* __restrict__ Wtk,
    const __bf16* __restrict__ Wtv, const __bf16* __restrict__ Xq,
    const __bf16* __restrict__ Xk, const __bf16* __restrict__ Xv,
    const float* __restrict__ bq, const float* __restrict__ bk,
    const float* __restrict__ bv, __bf16* __restrict__ Qh,
    __bf16* __restrict__ Kh, __bf16* __restrict__ Vt) {
  __shared__ __align__(16) __bf16 As[128 * 32];
  __shared__ __align__(16) __bf16 Bs[128 * 32];
  const int z = blockIdx.z;
  const __bf16* Aop = (z == 0) ? Wtq : (z == 1) ? Wtk : Wtv;
  const __bf16* Bop = (z == 0) ? Xq : (z == 1) ? Xk : Xv;
  const float* bias = (z == 0) ? bq : (z == 1) ? bk : bv;
  __bf16* Dst = (z == 0) ? Qh : (z == 1) ? Kh : Vt;
  const int m0 = blockIdx.x * 128, n0 = blockIdx.y * 128;

  const int tid = threadIdx.x, lane = tid & 63, w = tid >> 6;
  const int quad = lane >> 4, l16 = lane & 15;
  const int wm = (w >> 1) * 64, wn = (w & 1) * 64;

  // staging (64 B rows): wave w insts j=0,1 -> rows w*32 + j*16 + (lane>>2)
  const int grow = w * 32 + (lane >> 2);
  const int gcol = (lane & 3) * 8;
  const __bf16* gA = Aop + (size_t)(m0 + grow) * 768 + gcol;
  const __bf16* gB = Bop + (size_t)(n0 + grow) * 768 + gcol;
  __bf16* lA = As + w * 1024;  // chunks of 512 elems per inst
  __bf16* lB = Bs + w * 1024;

  floatx4 acc[4][4] = {};

  for (int k0 = 0; k0 < 768; k0 += 32) {
    __syncthreads();
    glds16(gA, lA);
    glds16(gA + (size_t)16 * 768, lA + 512);
    glds16(gB, lB);
    glds16(gB + (size_t)16 * 768, lB + 512);
    gA += 32;
    gB += 32;
    __syncthreads();
    bf16x8 af[4], bfr[4];
#pragma unroll
    for (int t = 0; t < 4; ++t) {
      af[t] = *(const bf16x8*)&As[(wm + t * 16 + l16) * 32 + quad * 8];
      bfr[t] = *(const bf16x8*)&Bs[(wn + t * 16 + l16) * 32 + quad * 8];
    }
#pragma unroll
    for (int mt = 0; mt < 4; ++mt)
#pragma unroll
      for (int nt = 0; nt < 4; ++nt)
        acc[mt][nt] = MFMA_BF16(af[mt], bfr[nt], acc[mt][nt]);
  }

  // epilogue
#pragma unroll
  for (int mt = 0; mt < 4; ++mt) {
    const int e = m0 + wm + mt * 16 + quad * 4;
    const float4 b4 = *(const float4*)&bias[e];
    const int h = e >> 6, d = e & 63;
#pragma unroll
    for (int nt = 0; nt < 4; ++nt) {
      const int s = n0 + wn + nt * 16 + l16;
      const int bb = s >> 11, sr = s & 2047;
      const float v0 = acc[mt][nt][0] + b4.x;
      const float v1 = acc[mt][nt][1] + b4.y;
      const float v2 = acc[mt][nt][2] + b4.z;
      const float v3 = acc[mt][nt][3] + b4.w;
      if (z < 2) {
        bf16x4 pv;
        pv[0] = (__bf16)v0; pv[1] = (__bf16)v1; pv[2] = (__bf16)v2; pv[3] = (__bf16)v3;
        // z==1 (K): swizzle d-block by s&7 so attn LDS reads are conflict-free
        const int col = (z == 0) ? d : ((((d >> 3) ^ (sr & 7)) << 3) | (d & 7));
        *(bf16x4*)&Dst[((size_t)(bb * 12 + h) * 2048 + sr) * 64 + col] = pv;
      } else {
        // V^T: swizzle key-block within each 64-key window by (d+r)&7
        const size_t rowbase = ((size_t)(bb * 12 + h) * 64 + d) * 2048;
        const int shi = sr & ~63, sblk = (sr >> 3) & 7, soff = sr & 7;
        Dst[rowbase + 0 * 2048 + shi + (((sblk ^ ((d + 0) & 7))) << 3) + soff] = (__bf16)v0;
        Dst[rowbase + 1 * 2048 + shi + (((sblk ^ ((d + 1) & 7))) << 3) + soff] = (__bf16)v1;
        Dst[rowbase + 2 * 2048 + shi + (((sblk ^ ((d + 2) & 7))) << 3) + soff] = (__bf16)v2;
        Dst[rowbase + 3 * 2048 + shi + (((sblk ^ ((d + 3) & 7))) << 3) + soff] = (__bf16)v3;
      }
    }
  }
}

// ---------------------------------------------------------------------------
// Output projection GEMM. grid (6, 64), block 256. Both operands bf16, glds.
// ---------------------------------------------------------------------------
__global__ __launch_bounds__(256) void out_gemm(const __bf16* __restrict__ Wto,
                                                const __bf16* __restrict__ Ctx,
                                                const float* __restrict__ bo,
                                                float* __restrict__ Out) {
  __shared__ __align__(16) __bf16 As[128 * 32];
  __shared__ __align__(16) __bf16 Bs[128 * 32];
  const int m0 = blockIdx.x * 128, n0 = blockIdx.y * 128;
  const int tid = threadIdx.x, lane = tid & 63, w = tid >> 6;
  const int quad = lane >> 4, l16 = lane & 15;
  const int wm = (w >> 1) * 64, wn = (w & 1) * 64;

  const int grow = w * 32 + (lane >> 2);
  const int gcol = (lane & 3) * 8;
  const __bf16* gA = Wto + (size_t)(m0 + grow) * 768 + gcol;
  const __bf16* gB = Ctx + (size_t)(n0 + grow) * 768 + gcol;
  __bf16* lA = As + w * 1024;
  __bf16* lB = Bs + w * 1024;

  floatx4 acc[4][4] = {};
  for (int k0 = 0; k0 < 768; k0 += 32) {
    __syncthreads();
    glds16(gA, lA);
    glds16(gA + (size_t)16 * 768, lA + 512);
    glds16(gB, lB);
    glds16(gB + (size_t)16 * 768, lB + 512);
    gA += 32;
    gB += 32;
    __syncthreads();
    bf16x8 af[4], bfr[4];
#pragma unroll
    for (int t = 0; t < 4; ++t) {
      af[t] = *(const bf16x8*)&As[(wm + t * 16 + l16) * 32 + quad * 8];
      bfr[t] = *(const bf16x8*)&Bs[(wn + t * 16 + l16) * 32 + quad * 8];
    }
#pragma unroll
    for (int mt = 0; mt < 4; ++mt)
#pragma unroll
      for (int nt = 0; nt < 4; ++nt)
        acc[mt][nt] = MFMA_BF16(af[mt], bfr[nt], acc[mt][nt]);
  }

#pragma unroll
  for (int mt = 0; mt < 4; ++mt) {
    const int e = m0 + wm + mt * 16 + quad * 4;
    const float4 b4 = *(const float4*)&bo[e];
#pragma unroll
    for (int nt = 0; nt < 4; ++nt) {
      const int s = n0 + wn + nt * 16 + l16;
      float4 r;
      r.x = acc[mt][nt][0] + b4.x;
      r.y = acc[mt][nt][1] + b4.y;
      r.z = acc[mt][nt][2] + b4.z;
      r.w = acc[mt][nt][3] + b4.w;
      *(float4*)&Out[(size_t)s * 768 + e] = r;
    }
  }
}

// ---------------------------------------------------------------------------
// Flash attention, shared-LDS K/V tiles with XOR-swizzled layouts.
// grid (16, 48), block 256 (4 waves). Per 64-key tile: stage K[64key][64d]
// (d-blocks swizzled by key&7) and V[64d][64key] (key-blocks swizzled by
// d&7) via glds16. Fragment reads use block = quad ^ (l16&7) -> banks spread
// across all 32 (2-way, free). S^T = K Q^T; fixed-ref softmax (exp2);
// P^T via per-wave LDS (no barrier); O^T = V^T P^T.
// ---------------------------------------------------------------------------
__global__ __launch_bounds__(256) void attn_kernel(
    const __bf16* __restrict__ Qh, const __bf16* __restrict__ Kh,
    const __bf16* __restrict__ Vt, const int* __restrict__ mask,
    __bf16* __restrict__ ctx) {
  const int bh = blockIdx.y, b = bh / 12, h = bh - b * 12;
  const int tid = threadIdx.x, lane = tid & 63, w = tid >> 6;
  const int quad = lane >> 4, l16 = lane & 15;
  const int q0 = blockIdx.x * 128 + w * 32;

  __shared__ float biasS[2048];
  __shared__ __align__(16) __bf16 Ks[64 * 64];        // [key][d-swz]
  __shared__ __align__(16) __bf16 Vs[64 * 64];        // [d][key-swz]
  __shared__ __align__(16) __bf16 Plds[4][32][72];    // [wave][q][key(+pad)]

  for (int i = tid; i < 2048; i += 256)
    biasS[i] = mask[b * 2048 + i] ? 0.0f : -1e5f;
  __syncthreads();

  const __bf16* Qbase = Qh + (size_t)bh * 2048 * 64;
  const __bf16* Kbase = Kh + (size_t)bh * 2048 * 64;
  const __bf16* Vbase = Vt + (size_t)bh * 64 * 2048;

  // Q B-frags (plain layout): B[k=d][n=q] from Qh[q][d]
  bf16x8 bqf[2][2];
#pragma unroll
  for (int qt = 0; qt < 2; ++qt)
#pragma unroll
    for (int c = 0; c < 2; ++c)
      bqf[qt][c] =
          *(const bf16x8*)&Qbase[(size_t)(q0 + qt * 16 + l16) * 64 + c * 32 + quad * 8];

  // staging (128 B rows): chunk c covers rows c*8 + (lane>>3), col (lane&7)*8
  const int srow = (lane >> 3);
  const int scol = (lane & 7) * 8;
  // swizzled fragment column base: block = quad ^ (l16&7)
  const int col0 = (quad ^ (l16 & 7)) * 8;

  floatx4 o[4][2] = {};  // O^T accs: [d-tile][q-tile]
  float rS[2] = {0.0f, 0.0f};
  const float SC = 0.18033688011112042f;  // 0.125 * log2(e)

  for (int kt = 0; kt < 2048; kt += 64) {
    __syncthreads();  // prior-iter LDS reads done
#pragma unroll
    for (int j = 0; j < 2; ++j) {
      const int c = w * 2 + j;
      const int row = c * 8 + srow;
      glds16(&Kbase[(size_t)(kt + row) * 64 + scol], Ks + c * 512);
      glds16(&Vbase[(size_t)row * 2048 + kt + scol], Vs + c * 512);
    }
    __syncthreads();  // staging visible

    // ---- scores S^T: 4 key-tiles x 2 q-tiles
    floatx4 sc[4][2];
#pragma unroll
    for (int t = 0; t < 4; ++t) {
      bf16x8 ak0 = *(const bf16x8*)&Ks[(t * 16 + l16) * 64 + col0];
      bf16x8 ak1 = *(const bf16x8*)&Ks[(t * 16 + l16) * 64 + (col0 ^ 32)];
#pragma unroll
      for (int qt = 0; qt < 2; ++qt) {
        floatx4 zz = {};
        zz = MFMA_BF16(ak0, bqf[qt][0], zz);
        zz = MFMA_BF16(ak1, bqf[qt][1], zz);
        sc[t][qt] = zz;
      }
    }
    // ---- p = exp2(s*SC + bias2[key]); accumulate per-lane sums
#pragma unroll
    for (int t = 0; t < 4; ++t) {
      const float4 kb = *(const float4*)&biasS[kt + t * 16 + quad * 4];
#pragma unroll
      for (int qt = 0; qt < 2; ++qt) {
        floatx4 p;
        p[0] = exp2f(fmaf(sc[t][qt][0], SC, kb.x));
        p[1] = exp2f(fmaf(sc[t][qt][1], SC, kb.y));
        p[2] = exp2f(fmaf(sc[t][qt][2], SC, kb.z));
        p[3] = exp2f(fmaf(sc[t][qt][3], SC, kb.w));
        sc[t][qt] = p;
        rS[qt] += p[0] + p[1] + p[2] + p[3];
      }
    }
    // ---- pack P^T into Plds[q][key] (4 consecutive keys/lane -> b64)
#pragma unroll
    for (int qt = 0; qt < 2; ++qt)
#pragma unroll
      for (int t = 0; t < 4; ++t) {
        bf16x4 pv;
        pv[0] = (__bf16)sc[t][qt][0];
        pv[1] = (__bf16)sc[t][qt][1];
        pv[2] = (__bf16)sc[t][qt][2];
        pv[3] = (__bf16)sc[t][qt][3];
        *(bf16x4*)&Plds[w][qt * 16 + l16][t * 16 + quad * 4] = pv;
      }
    // ---- O^T += V^T @ P^T  (per-wave Plds; in-wave lgkmcnt only)
#pragma unroll
    for (int c = 0; c < 2; ++c) {
      bf16x8 bp[2];
#pragma unroll
      for (int qt = 0; qt < 2; ++qt)
        bp[qt] = *(const bf16x8*)&Plds[w][qt * 16 + l16][c * 32 + quad * 8];
#pragma unroll
      for (int dt = 0; dt < 4; ++dt) {
        bf16x8 av = *(const bf16x8*)&Vs[(dt * 16 + l16) * 64 + (col0 ^ (c * 32))];
#pragma unroll
        for (int qt = 0; qt < 2; ++qt) o[dt][qt] = MFMA_BF16(av, bp[qt], o[dt][qt]);
      }
    }
  }

  // ---- cross-lane sum (across quads) + normalize + write ctx
  float inv[2];
#pragma unroll
  for (int qt = 0; qt < 2; ++qt) {
    float s = rS[qt];
    s += __shfl_xor(s, 16, 64);
    s += __shfl_xor(s, 32, 64);
    inv[qt] = 1.0f / s;
  }
#pragma unroll
  for (int dt = 0; dt < 4; ++dt)
#pragma unroll
    for (int qt = 0; qt < 2; ++qt) {
      const int q = q0 + qt * 16 + l16;
      const int d = h * 64 + dt * 16 + quad * 4;
      bf16x4 pv;
      pv[0] = (__bf16)(o[dt][qt][0] * inv[qt]);
      pv[1] = (__bf16)(o[dt][qt][1] * inv[qt]);
      pv[2] = (__bf16)(o[dt][qt][2] * inv[qt]);
      pv[3] = (__bf16)(o[dt][qt][3] * inv[qt]);
      *(bf16x4*)&ctx[(size_t)(b * 2048 + q) * 768 + d] = pv;
    }
}

// ---------------------------------------------------------------------------
extern "C" void kernel_launch(void* const* d_in, const int* in_sizes, int n_in,
                              void* d_out, int out_size, void* d_ws, size_t ws_size,
                              hipStream_t stream) {
  const float* q = (const float*)d_in[0];
  const float* k = (const float*)d_in[1];
  const float* v = (const float*)d_in[2];
  const int* mask = (const int*)d_in[3];
  const float* Wq = (const float*)d_in[4];
  const float* bq = (const float*)d_in[5];
  const float* Wk = (const float*)d_in[6];
  const float* bk = (const float*)d_in[7];
  const float* Wv = (const float*)d_in[8];
  const float* bv = (const float*)d_in[9];
  const float* Wo = (const float*)d_in[10];
  const float* bo = (const float*)d_in[11];
  float* out = (float*)d_out;

  char* ws = (char*)d_ws;
  const size_t SZ = (size_t)8192 * 768 * 2;   // 12.58 MB
  const size_t WSZ = (size_t)768 * 768 * 2;   // 1.18 MB
  __bf16* Xq = (__bf16*)(ws);
  __bf16* Xk = (__bf16*)(ws + SZ);
  __bf16* Xv = (__bf16*)(ws + 2 * SZ);
  __bf16* Qh = (__bf16*)(ws + 3 * SZ);
  __bf16* Kh = (__bf16*)(ws + 4 * SZ);
  __bf16* Vt = (__bf16*)(ws + 5 * SZ);
  __bf16* ctx = (__bf16*)(ws + 6 * SZ);
  __bf16* Wtq = (__bf16*)(ws + 7 * SZ);
  __bf16* Wtk = (__bf16*)(ws + 7 * SZ + WSZ);
  __bf16* Wtv = (__bf16*)(ws + 7 * SZ + 2 * WSZ);
  __bf16* Wto = (__bf16*)(ws + 7 * SZ + 3 * WSZ);

  prep_convert<<<dim3(3072, 3), 256, 0, stream>>>(q, k, v, Xq, Xk, Xv);
  prep_transpose<<<dim3(24, 24, 4), 256, 0, stream>>>(Wq, Wk, Wv, Wo, Wtq, Wtk, Wtv, Wto);
  qkv_gemm<<<dim3(6, 64, 3), 256, 0, stream>>>(Wtq, Wtk, Wtv, Xq, Xk, Xv, bq, bk, bv,
                                               Qh, Kh, Vt);
  attn_kernel<<<dim3(16, 48), 256, 0, stream>>>(Qh, Kh, Vt, mask, ctx);
  out_gemm<<<dim3(6, 64), 256, 0, stream>>>(Wto, ctx, bo, out);
}

// Round 7
// 309.341 us; speedup vs baseline: 1.7752x; 1.0351x over previous
//
#include <hip/hip_runtime.h>
#include <hip/hip_bf16.h>
#include <stdint.h>

// MultiHeadAttention fused pipeline for MI355X (gfx950).
// B=4, S=2048, E=768, H=12, D=64.
//  prep_transpose: W fp32 -> Wt bf16 (Wt[n][k] = W[k][n])
//  qkv_gemm (z): C[m=e][n=s] = Wt (glds) x X^T (fp32 inline-converted).
//     Epilogue: z=0 Qh plain [BH][S][64]; z=1 Kh d-block XOR-swizzled by s&7;
//     z=2 Vt [BH][64][S], key-block XOR-swizzled by d&7 per 64-key window.
//  attn: double-buffered K/V LDS tiles, ONE barrier per 64-key tile (glds
//     prefetch of tile i+1 overlaps compute of tile i), S^T = K Q^T,
//     fixed-ref softmax via raw v_exp_f32, mask from global int4.
//  out_gemm: C[m=e][n=s] = Wto x ctx^T, float4 stores.

typedef __bf16 bf16x8 __attribute__((ext_vector_type(8)));
typedef __bf16 bf16x4 __attribute__((ext_vector_type(4)));
typedef float floatx4 __attribute__((ext_vector_type(4)));

#define MFMA_BF16(a, b, c) __builtin_amdgcn_mfma_f32_16x16x32_bf16(a, b, c, 0, 0, 0)

// MFMA 16x16x32 layouts (verified, learn_hip m89/m91):
//   A frag: A[m = lane&15][k = (lane>>4)*8 + j]
//   B frag: B[k = (lane>>4)*8 + j][n = lane&15]   (read from [n][k] storage)
//   C/D  : C[m = (lane>>4)*4 + r][n = lane&15]
// glds16: 64 lanes x 16 B = 1024 B per instruction, dest = uniform base +
// lane*16B. 128B rows -> 8 rows/chunk (lane>>3, (lane&7)*8); 64B rows ->
// 16 rows/chunk (lane>>2, (lane&3)*8).

__device__ __forceinline__ void glds16(const __bf16* g, __bf16* l) {
  __builtin_amdgcn_global_load_lds(
      (const __attribute__((address_space(1))) unsigned int*)g,
      (__attribute__((address_space(3))) unsigned int*)l, 16, 0, 0);
}

// ---------------------------------------------------------------------------
// prep: transpose+convert weights. grid (24, 24, 4), block 256.
// ---------------------------------------------------------------------------
__global__ __launch_bounds__(256) void prep_transpose(
    const float* __restrict__ W0, const float* __restrict__ W1,
    const float* __restrict__ W2, const float* __restrict__ W3,
    __bf16* __restrict__ T0, __bf16* __restrict__ T1,
    __bf16* __restrict__ T2, __bf16* __restrict__ T3) {
  const int z = blockIdx.z;
  const float* W = (z == 0) ? W0 : (z == 1) ? W1 : (z == 2) ? W2 : W3;
  __bf16* T = (z == 0) ? T0 : (z == 1) ? T1 : (z == 2) ? T2 : T3;
  __shared__ float t[32][33];
  const int tx = threadIdx.x & 31, ty = threadIdx.x >> 5;
  const int kb = blockIdx.x * 32, nb = blockIdx.y * 32;
#pragma unroll
  for (int j = 0; j < 4; ++j)
    t[ty + j * 8][tx] = W[(size_t)(kb + ty + j * 8) * 768 + nb + tx];
  __syncthreads();
#pragma unroll
  for (int j = 0; j < 4; ++j)
    T[(size_t)(nb + ty + j * 8) * 768 + kb + tx] = (__bf16)t[tx][ty + j * 8];
}

// ---------------------------------------------------------------------------
// QKV projection GEMM. grid (6, 64, 3), block 256.
// A = Wt (bf16, glds16). B = X (fp32 row-major [8192][768]) staged with
// inline fp32->bf16 convert. C[m=e][n=s]. Tile 128x128, BK=32.
// ---------------------------------------------------------------------------
__global__ __launch_bounds__(256) void qkv_gemm(
    const __bf16* __restrict__ Wtq, const __bf16* __restrict__ Wtk,
    const __bf16* __restrict__ Wtv, const float* __restrict__ Xq,
    const float* __restrict__ Xk, const float* __restrict__ Xv,
    const float* __restrict__ bq, const float* __restrict__ bk,
    const float* __restrict__ bv, __bf16* __restrict__ Qh,
    __bf16* __restrict__ Kh, __bf16* __restrict__ Vt) {
  __shared__ __align__(16) __bf16 As[128 * 32];
  __shared__ __align__(16) __bf16 Bs[128 * 32];
  const int z = blockIdx.z;
  const __bf16* Aop = (z == 0) ? Wtq : (z == 1) ? Wtk : Wtv;
  const float* Bop = (z == 0) ? Xq : (z == 1) ? Xk : Xv;
  const float* bias = (z == 0) ? bq : (z == 1) ? bk : bv;
  __bf16* Dst = (z == 0) ? Qh : (z == 1) ? Kh : Vt;
  const int m0 = blockIdx.x * 128, n0 = blockIdx.y * 128;

  const int tid = threadIdx.x, lane = tid & 63, w = tid >> 6;
  const int quad = lane >> 4, l16 = lane & 15;
  const int wm = (w >> 1) * 64, wn = (w & 1) * 64;

  // A staging (glds, 64 B rows): wave w insts j=0,1 -> rows w*32+j*16+(lane>>2)
  const int garow = w * 32 + (lane >> 2);
  const int gacol = (lane & 3) * 8;
  const __bf16* gA = Aop + (size_t)(m0 + garow) * 768 + gacol;
  __bf16* lA = As + w * 1024;  // chunks of 512 elems per inst
  // B staging (explicit fp32): pass j covers rows (tid>>3)+32j, col (tid&7)*4
  const int brow = tid >> 3, bcol = (tid & 7) * 4;

  floatx4 acc[4][4] = {};

  for (int k0 = 0; k0 < 768; k0 += 32) {
    __syncthreads();
    glds16(gA, lA);
    glds16(gA + (size_t)16 * 768, lA + 512);
    gA += 32;
    float4 f[4];
#pragma unroll
    for (int j = 0; j < 4; ++j)
      f[j] = *(const float4*)&Bop[(size_t)(n0 + brow + 32 * j) * 768 + k0 + bcol];
#pragma unroll
    for (int j = 0; j < 4; ++j) {
      bf16x4 pv;
      pv[0] = (__bf16)f[j].x; pv[1] = (__bf16)f[j].y;
      pv[2] = (__bf16)f[j].z; pv[3] = (__bf16)f[j].w;
      *(bf16x4*)&Bs[(brow + 32 * j) * 32 + bcol] = pv;
    }
    __syncthreads();
    bf16x8 af[4], bfr[4];
#pragma unroll
    for (int t = 0; t < 4; ++t) {
      af[t] = *(const bf16x8*)&As[(wm + t * 16 + l16) * 32 + quad * 8];
      bfr[t] = *(const bf16x8*)&Bs[(wn + t * 16 + l16) * 32 + quad * 8];
    }
#pragma unroll
    for (int mt = 0; mt < 4; ++mt)
#pragma unroll
      for (int nt = 0; nt < 4; ++nt)
        acc[mt][nt] = MFMA_BF16(af[mt], bfr[nt], acc[mt][nt]);
  }

  // epilogue
#pragma unroll
  for (int mt = 0; mt < 4; ++mt) {
    const int e = m0 + wm + mt * 16 + quad * 4;
    const float4 b4 = *(const float4*)&bias[e];
    const int h = e >> 6, d = e & 63;
#pragma unroll
    for (int nt = 0; nt < 4; ++nt) {
      const int s = n0 + wn + nt * 16 + l16;
      const int bb = s >> 11, sr = s & 2047;
      const float v0 = acc[mt][nt][0] + b4.x;
      const float v1 = acc[mt][nt][1] + b4.y;
      const float v2 = acc[mt][nt][2] + b4.z;
      const float v3 = acc[mt][nt][3] + b4.w;
      if (z < 2) {
        bf16x4 pv;
        pv[0] = (__bf16)v0; pv[1] = (__bf16)v1; pv[2] = (__bf16)v2; pv[3] = (__bf16)v3;
        // z==1 (K): swizzle d-block by s&7 so attn LDS reads are conflict-free
        const int col = (z == 0) ? d : ((((d >> 3) ^ (sr & 7)) << 3) | (d & 7));
        *(bf16x4*)&Dst[((size_t)(bb * 12 + h) * 2048 + sr) * 64 + col] = pv;
      } else {
        // V^T: swizzle key-block within each 64-key window by (d+r)&7
        const size_t rowbase = ((size_t)(bb * 12 + h) * 64 + d) * 2048;
        const int shi = sr & ~63, sblk = (sr >> 3) & 7, soff = sr & 7;
        Dst[rowbase + 0 * 2048 + shi + (((sblk ^ ((d + 0) & 7))) << 3) + soff] = (__bf16)v0;
        Dst[rowbase + 1 * 2048 + shi + (((sblk ^ ((d + 1) & 7))) << 3) + soff] = (__bf16)v1;
        Dst[rowbase + 2 * 2048 + shi + (((sblk ^ ((d + 2) & 7))) << 3) + soff] = (__bf16)v2;
        Dst[rowbase + 3 * 2048 + shi + (((sblk ^ ((d + 3) & 7))) << 3) + soff] = (__bf16)v3;
      }
    }
  }
}

// ---------------------------------------------------------------------------
// Output projection GEMM. grid (6, 64), block 256. Both operands bf16, glds.
// ---------------------------------------------------------------------------
__global__ __launch_bounds__(256) void out_gemm(const __bf16* __restrict__ Wto,
                                                const __bf16* __restrict__ Ctx,
                                                const float* __restrict__ bo,
                                                float* __restrict__ Out) {
  __shared__ __align__(16) __bf16 As[128 * 32];
  __shared__ __align__(16) __bf16 Bs[128 * 32];
  const int m0 = blockIdx.x * 128, n0 = blockIdx.y * 128;
  const int tid = threadIdx.x, lane = tid & 63, w = tid >> 6;
  const int quad = lane >> 4, l16 = lane & 15;
  const int wm = (w >> 1) * 64, wn = (w & 1) * 64;

  const int grow = w * 32 + (lane >> 2);
  const int gcol = (lane & 3) * 8;
  const __bf16* gA = Wto + (size_t)(m0 + grow) * 768 + gcol;
  const __bf16* gB = Ctx + (size_t)(n0 + grow) * 768 + gcol;
  __bf16* lA = As + w * 1024;
  __bf16* lB = Bs + w * 1024;

  floatx4 acc[4][4] = {};
  for (int k0 = 0; k0 < 768; k0 += 32) {
    __syncthreads();
    glds16(gA, lA);
    glds16(gA + (size_t)16 * 768, lA + 512);
    glds16(gB, lB);
    glds16(gB + (size_t)16 * 768, lB + 512);
    gA += 32;
    gB += 32;
    __syncthreads();
    bf16x8 af[4], bfr[4];
#pragma unroll
    for (int t = 0; t < 4; ++t) {
      af[t] = *(const bf16x8*)&As[(wm + t * 16 + l16) * 32 + quad * 8];
      bfr[t] = *(const bf16x8*)&Bs[(wn + t * 16 + l16) * 32 + quad * 8];
    }
#pragma unroll
    for (int mt = 0; mt < 4; ++mt)
#pragma unroll
      for (int nt = 0; nt < 4; ++nt)
        acc[mt][nt] = MFMA_BF16(af[mt], bfr[nt], acc[mt][nt]);
  }

#pragma unroll
  for (int mt = 0; mt < 4; ++mt) {
    const int e = m0 + wm + mt * 16 + quad * 4;
    const float4 b4 = *(const float4*)&bo[e];
#pragma unroll
    for (int nt = 0; nt < 4; ++nt) {
      const int s = n0 + wn + nt * 16 + l16;
      float4 r;
      r.x = acc[mt][nt][0] + b4.x;
      r.y = acc[mt][nt][1] + b4.y;
      r.z = acc[mt][nt][2] + b4.z;
      r.w = acc[mt][nt][3] + b4.w;
      *(float4*)&Out[(size_t)s * 768 + e] = r;
    }
  }
}

// ---------------------------------------------------------------------------
// Flash attention, double-buffered shared-LDS K/V tiles, ONE barrier/iter.
// grid (16, 48), block 256 (4 waves). Iter i: barrier (tile-i staging from
// iter i-1 drains here, after a full compute phase in flight); issue glds
// prefetch of tile i+1 into the other buffer; compute tile i. The prefetch
// buffer was last read in iter i-1 (finished before this barrier) -> safe.
// Swizzled K/V layouts (block ^= row&7) keep LDS frag reads ~conflict-free.
// S^T = K Q^T; softmax via raw v_exp_f32 (scores O(10), no denormal risk);
// mask int4 from global (L1-resident). P^T via per-wave LDS (no barrier).
// ---------------------------------------------------------------------------
__global__ __launch_bounds__(256) void attn_kernel(
    const __bf16* __restrict__ Qh, const __bf16* __restrict__ Kh,
    const __bf16* __restrict__ Vt, const int* __restrict__ mask,
    __bf16* __restrict__ ctx) {
  const int bh = blockIdx.y, b = bh / 12, h = bh - b * 12;
  const int tid = threadIdx.x, lane = tid & 63, w = tid >> 6;
  const int quad = lane >> 4, l16 = lane & 15;
  const int q0 = blockIdx.x * 128 + w * 32;

  __shared__ __align__(16) __bf16 Ks[2][64 * 64];     // [buf][key][d-swz]
  __shared__ __align__(16) __bf16 Vs[2][64 * 64];     // [buf][d][key-swz]
  __shared__ __align__(16) __bf16 Plds[4][32][72];    // [wave][q][key(+pad)]

  const __bf16* Qbase = Qh + (size_t)bh * 2048 * 64;
  const __bf16* Kbase = Kh + (size_t)bh * 2048 * 64;
  const __bf16* Vbase = Vt + (size_t)bh * 64 * 2048;
  const int* maskB = mask + b * 2048;

  // Q B-frags (plain layout): B[k=d][n=q] from Qh[q][d]
  bf16x8 bqf[2][2];
#pragma unroll
  for (int qt = 0; qt < 2; ++qt)
#pragma unroll
    for (int c = 0; c < 2; ++c)
      bqf[qt][c] =
          *(const bf16x8*)&Qbase[(size_t)(q0 + qt * 16 + l16) * 64 + c * 32 + quad * 8];

  // staging (128 B rows): chunk c covers rows c*8 + (lane>>3), col (lane&7)*8
  const int r0 = (w * 2) * 8 + (lane >> 3);
  const int r1 = (w * 2 + 1) * 8 + (lane >> 3);
  const int scol = (lane & 7) * 8;
  const int d0 = (w * 2) * 512;      // LDS chunk offsets (elems)
  const int d1 = (w * 2 + 1) * 512;
  // swizzled fragment column base: block = quad ^ (l16&7)
  const int col0 = (quad ^ (l16 & 7)) * 8;

  // prologue: stage tile 0 into buffer 0
  glds16(&Kbase[(size_t)r0 * 64 + scol], &Ks[0][d0]);
  glds16(&Kbase[(size_t)r1 * 64 + scol], &Ks[0][d1]);
  glds16(&Vbase[(size_t)r0 * 2048 + scol], &Vs[0][d0]);
  glds16(&Vbase[(size_t)r1 * 2048 + scol], &Vs[0][d1]);

  floatx4 o[4][2] = {};  // O^T accs: [d-tile][q-tile]
  float rS[2] = {0.0f, 0.0f};
  const float SC = 0.18033688011112042f;  // 0.125 * log2(e)

  for (int it = 0; it < 32; ++it) {
    const int kt = it * 64;
    const int cur = it & 1;
    const int nxt = cur ^ 1;
    const int nkt = (kt + 64) & 2047;  // wrap: last-iter prefetch is harmless

    __syncthreads();  // drains tile-`it` staging (in flight since iter it-1)

    // ---- prefetch tile it+1 into the other buffer (overlaps compute below)
    glds16(&Kbase[(size_t)(nkt + r0) * 64 + scol], &Ks[nxt][d0]);
    glds16(&Kbase[(size_t)(nkt + r1) * 64 + scol], &Ks[nxt][d1]);
    glds16(&Vbase[(size_t)r0 * 2048 + nkt + scol], &Vs[nxt][d0]);
    glds16(&Vbase[(size_t)r1 * 2048 + nkt + scol], &Vs[nxt][d1]);

    // ---- mask bias for this tile (L1-resident int4 loads)
    int4 mk[4];
#pragma unroll
    for (int t = 0; t < 4; ++t) mk[t] = *(const int4*)&maskB[kt + t * 16 + quad * 4];

    // ---- scores S^T: 4 key-tiles x 2 q-tiles
    floatx4 sc[4][2];
#pragma unroll
    for (int t = 0; t < 4; ++t) {
      bf16x8 ak0 = *(const bf16x8*)&Ks[cur][(t * 16 + l16) * 64 + col0];
      bf16x8 ak1 = *(const bf16x8*)&Ks[cur][(t * 16 + l16) * 64 + (col0 ^ 32)];
#pragma unroll
      for (int qt = 0; qt < 2; ++qt) {
        floatx4 zz = {};
        zz = MFMA_BF16(ak0, bqf[qt][0], zz);
        zz = MFMA_BF16(ak1, bqf[qt][1], zz);
        sc[t][qt] = zz;
      }
    }
    // ---- p = exp2(s*SC + bias); per-lane partial sums
#pragma unroll
    for (int t = 0; t < 4; ++t) {
      const float k0f = mk[t].x ? 0.0f : -1e5f;
      const float k1f = mk[t].y ? 0.0f : -1e5f;
      const float k2f = mk[t].z ? 0.0f : -1e5f;
      const float k3f = mk[t].w ? 0.0f : -1e5f;
#pragma unroll
      for (int qt = 0; qt < 2; ++qt) {
        floatx4 p;
        p[0] = __builtin_amdgcn_exp2f(fmaf(sc[t][qt][0], SC, k0f));
        p[1] = __builtin_amdgcn_exp2f(fmaf(sc[t][qt][1], SC, k1f));
        p[2] = __builtin_amdgcn_exp2f(fmaf(sc[t][qt][2], SC, k2f));
        p[3] = __builtin_amdgcn_exp2f(fmaf(sc[t][qt][3], SC, k3f));
        sc[t][qt] = p;
        rS[qt] += p[0] + p[1] + p[2] + p[3];
      }
    }
    // ---- pack P^T into Plds[q][key] (4 consecutive keys/lane -> b64)
#pragma unroll
    for (int qt = 0; qt < 2; ++qt)
#pragma unroll
      for (int t = 0; t < 4; ++t) {
        bf16x4 pv;
        pv[0] = (__bf16)sc[t][qt][0];
        pv[1] = (__bf16)sc[t][qt][1];
        pv[2] = (__bf16)sc[t][qt][2];
        pv[3] = (__bf16)sc[t][qt][3];
        *(bf16x4*)&Plds[w][qt * 16 + l16][t * 16 + quad * 4] = pv;
      }
    // ---- O^T += V^T @ P^T  (per-wave Plds; in-wave lgkmcnt only)
#pragma unroll
    for (int c = 0; c < 2; ++c) {
      bf16x8 bp[2];
#pragma unroll
      for (int qt = 0; qt < 2; ++qt)
        bp[qt] = *(const bf16x8*)&Plds[w][qt * 16 + l16][c * 32 + quad * 8];
#pragma unroll
      for (int dt = 0; dt < 4; ++dt) {
        bf16x8 av = *(const bf16x8*)&Vs[cur][(dt * 16 + l16) * 64 + (col0 ^ (c * 32))];
#pragma unroll
        for (int qt = 0; qt < 2; ++qt) o[dt][qt] = MFMA_BF16(av, bp[qt], o[dt][qt]);
      }
    }
  }

  // ---- cross-lane sum (across quads) + normalize + write ctx
  float inv[2];
#pragma unroll
  for (int qt = 0; qt < 2; ++qt) {
    float s = rS[qt];
    s += __shfl_xor(s, 16, 64);
    s += __shfl_xor(s, 32, 64);
    inv[qt] = 1.0f / s;
  }
#pragma unroll
  for (int dt = 0; dt < 4; ++dt)
#pragma unroll
    for (int qt = 0; qt < 2; ++qt) {
      const int q = q0 + qt * 16 + l16;
      const int d = h * 64 + dt * 16 + quad * 4;
      bf16x4 pv;
      pv[0] = (__bf16)(o[dt][qt][0] * inv[qt]);
      pv[1] = (__bf16)(o[dt][qt][1] * inv[qt]);
      pv[2] = (__bf16)(o[dt][qt][2] * inv[qt]);
      pv[3] = (__bf16)(o[dt][qt][3] * inv[qt]);
      *(bf16x4*)&ctx[(size_t)(b * 2048 + q) * 768 + d] = pv;
    }
}

// ---------------------------------------------------------------------------
extern "C" void kernel_launch(void* const* d_in, const int* in_sizes, int n_in,
                              void* d_out, int out_size, void* d_ws, size_t ws_size,
                              hipStream_t stream) {
  const float* q = (const float*)d_in[0];
  const float* k = (const float*)d_in[1];
  const float* v = (const float*)d_in[2];
  const int* mask = (const int*)d_in[3];
  const float* Wq = (const float*)d_in[4];
  const float* bq = (const float*)d_in[5];
  const float* Wk = (const float*)d_in[6];
  const float* bk = (const float*)d_in[7];
  const float* Wv = (const float*)d_in[8];
  const float* bv = (const float*)d_in[9];
  const float* Wo = (const float*)d_in[10];
  const float* bo = (const float*)d_in[11];
  float* out = (float*)d_out;

  char* ws = (char*)d_ws;
  const size_t SZ = (size_t)8192 * 768 * 2;   // 12.58 MB
  const size_t WSZ = (size_t)768 * 768 * 2;   // 1.18 MB
  __bf16* Qh = (__bf16*)(ws);
  __bf16* Kh = (__bf16*)(ws + SZ);
  __bf16* Vt = (__bf16*)(ws + 2 * SZ);
  __bf16* ctx = (__bf16*)(ws + 3 * SZ);
  __bf16* Wtq = (__bf16*)(ws + 4 * SZ);
  __bf16* Wtk = (__bf16*)(ws + 4 * SZ + WSZ);
  __bf16* Wtv = (__bf16*)(ws + 4 * SZ + 2 * WSZ);
  __bf16* Wto = (__bf16*)(ws + 4 * SZ + 3 * WSZ);

  prep_transpose<<<dim3(24, 24, 4), 256, 0, stream>>>(Wq, Wk, Wv, Wo, Wtq, Wtk, Wtv, Wto);
  qkv_gemm<<<dim3(6, 64, 3), 256, 0, stream>>>(Wtq, Wtk, Wtv, q, k, v, bq, bk, bv,
                                               Qh, Kh, Vt);
  attn_kernel<<<dim3(16, 48), 256, 0, stream>>>(Qh, Kh, Vt, mask, ctx);
  out_gemm<<<dim3(6, 64), 256, 0, stream>>>(Wto, ctx, bo, out);
}